// Round 3
// baseline (304.010 us; speedup 1.0000x reference)
//
#include <hip/hip_runtime.h>
#include <hip/hip_bf16.h>
#include <cstdint>

#define EMB 1024
#define HEADS 16
#define HD 64
#define BATCH 4
#define SEQ 2048
#define BT (BATCH*SEQ)                 // 8192 tokens
#define LNEPS 1e-5f
#define QK_SCALE 0.17677669529663687f  // 1024^-0.25
#define LOG2E 1.4426950408889634f

typedef __bf16 bf16;
typedef __bf16 bf16x8 __attribute__((ext_vector_type(8)));
typedef __bf16 bf16x4 __attribute__((ext_vector_type(4)));
typedef float  f32x4  __attribute__((ext_vector_type(4)));
typedef short  s16x4  __attribute__((ext_vector_type(4)));

typedef const __attribute__((address_space(1))) void* gas_ptr;
typedef __attribute__((address_space(3))) void*       las_ptr;

__device__ __forceinline__ void gld_lds16(const void* g, void* l) {
  __builtin_amdgcn_global_load_lds((gas_ptr)g, (las_ptr)l, 16, 0, 0);
}

// PV matmul: 16x16x16 bf16 MFMA (C-layout of S^T == B-layout of this shape).
__device__ __forceinline__ f32x4 mfma_pv(bf16x4 a, bf16x4 b, f32x4 c) {
  return __builtin_amdgcn_mfma_f32_16x16x16bf16_1k(
      __builtin_bit_cast(s16x4, a), __builtin_bit_cast(s16x4, b), c, 0, 0, 0);
}

// ---------------- fp32 -> bf16 conversion ----------------
__global__ void cvt_f32_bf16(const float* __restrict__ src, bf16* __restrict__ dst, int n4) {
  int i = blockIdx.x * blockDim.x + threadIdx.x;
  if (i >= n4) return;
  float4 f = reinterpret_cast<const float4*>(src)[i];
  bf16x4 o = { (bf16)f.x, (bf16)f.y, (bf16)f.z, (bf16)f.w };
  reinterpret_cast<bf16x4*>(dst)[i] = o;
}

// 4 weight matrices (1024x1024 each) -> contiguous bf16 [4*1024][1024]
__global__ void cvt_w4(const float* __restrict__ w0, const float* __restrict__ w1,
                       const float* __restrict__ w2, const float* __restrict__ w3,
                       bf16* __restrict__ dst) {
  int i = blockIdx.x * blockDim.x + threadIdx.x;   // over 4*262144 float4s
  int sel = i >> 18;
  int j = i & 262143;
  const float* s = (sel == 0) ? w0 : (sel == 1) ? w1 : (sel == 2) ? w2 : w3;
  float4 f = reinterpret_cast<const float4*>(s)[j];
  bf16x4 o = { (bf16)f.x, (bf16)f.y, (bf16)f.z, (bf16)f.w };
  reinterpret_cast<bf16x4*>(dst)[i] = o;
}

// ---------------- m97-style GEMM: C[M][N] = A[M][K] * B[N][K]^T ----------------
template<int OUTF32>
__global__ __launch_bounds__(256, 2) void gemm_bt(
    const bf16* __restrict__ A, const bf16* __restrict__ Bm,
    bf16* __restrict__ Cb, float* __restrict__ Cf, const float* __restrict__ bias,
    int M, int N, int K)
{
  __shared__ __align__(16) bf16 As[128 * 32];
  __shared__ __align__(16) bf16 Bs[128 * 32];

  const int t    = threadIdx.x;
  const int lane = t & 63;
  const int wave = t >> 6;
  const int q    = lane >> 4;
  const int ln   = lane & 15;
  const int m0   = blockIdx.y * 128;
  const int n0   = blockIdx.x * 128;
  const int wm   = (wave >> 1) * 64;
  const int wn   = (wave & 1) * 64;

  const int r0 = t >> 2;
  const int c0 = (t & 3) << 3;

  f32x4 zero4 = {0.f, 0.f, 0.f, 0.f};
  f32x4 acc[4][4];
#pragma unroll
  for (int i = 0; i < 4; i++)
#pragma unroll
    for (int j = 0; j < 4; j++) acc[i][j] = zero4;

  for (int k0 = 0; k0 < K; k0 += 32) {
    __syncthreads();
    const bf16* ga = A  + (size_t)(m0 + r0) * K + k0 + c0;
    const bf16* gb = Bm + (size_t)(n0 + r0) * K + k0 + c0;
    gld_lds16(ga,                  &As[t * 8]);
    gld_lds16(ga + (size_t)64 * K, &As[t * 8 + 2048]);
    gld_lds16(gb,                  &Bs[t * 8]);
    gld_lds16(gb + (size_t)64 * K, &Bs[t * 8 + 2048]);
    __syncthreads();

    bf16x8 af[4], bfr[4];
#pragma unroll
    for (int mi = 0; mi < 4; mi++)
      af[mi] = *reinterpret_cast<const bf16x8*>(&As[(wm + mi * 16 + ln) * 32 + q * 8]);
#pragma unroll
    for (int ni = 0; ni < 4; ni++)
      bfr[ni] = *reinterpret_cast<const bf16x8*>(&Bs[(wn + ni * 16 + ln) * 32 + q * 8]);
#pragma unroll
    for (int mi = 0; mi < 4; mi++)
#pragma unroll
      for (int ni = 0; ni < 4; ni++)
        acc[mi][ni] = __builtin_amdgcn_mfma_f32_16x16x32_bf16(af[mi], bfr[ni], acc[mi][ni], 0, 0, 0);
  }

#pragma unroll
  for (int mi = 0; mi < 4; mi++) {
#pragma unroll
    for (int ni = 0; ni < 4; ni++) {
#pragma unroll
      for (int r = 0; r < 4; r++) {
        int row = m0 + wm + mi * 16 + q * 4 + r;
        int col = n0 + wn + ni * 16 + ln;
        float v = acc[mi][ni][r];
        if (OUTF32) Cf[(size_t)row * N + col] = v + bias[col];
        else        Cb[(size_t)row * N + col] = (bf16)v;
      }
    }
  }
}

// ---------------- per-head LayerNorm for K and Q, vectorized ----------------
// kqv: [8192][3072]; K at col 0, Q at col 1024. Outputs [bh][t][64].
// 8 lanes per row, bf16x8 loads/stores. kscale includes log2(e).
__global__ void ln_kq(const bf16* __restrict__ kqv,
                      bf16* __restrict__ kn, bf16* __restrict__ qn,
                      const float* __restrict__ kg, const float* __restrict__ kb,
                      const float* __restrict__ qg, const float* __restrict__ qb,
                      float kscale, float qscale)
{
  const int t = threadIdx.x;
  const int lr = t & 7;                       // lane within row
  const int row = blockIdx.x * 32 + (t >> 3); // row = tok*16 + h
  const int tok = row >> 4, h = row & 15;
  const size_t base = (size_t)tok * (3 * EMB) + h * HD + lr * 8;

  bf16x8 vk = *reinterpret_cast<const bf16x8*>(kqv + base);
  bf16x8 vq = *reinterpret_cast<const bf16x8*>(kqv + base + EMB);

  float fk[8], fq[8];
  float sk = 0.f, sq = 0.f, s2k = 0.f, s2q = 0.f;
#pragma unroll
  for (int e = 0; e < 8; e++) {
    fk[e] = (float)vk[e]; fq[e] = (float)vq[e];
    sk += fk[e]; sq += fq[e];
    s2k += fk[e] * fk[e]; s2q += fq[e] * fq[e];
  }
#pragma unroll
  for (int m = 1; m < 8; m <<= 1) {
    sk  += __shfl_xor(sk,  m, 64); sq  += __shfl_xor(sq,  m, 64);
    s2k += __shfl_xor(s2k, m, 64); s2q += __shfl_xor(s2q, m, 64);
  }
  float mk = sk * (1.f / 64.f), mq = sq * (1.f / 64.f);
  float rk = rsqrtf(s2k * (1.f / 64.f) - mk * mk + LNEPS) * kscale;
  float rq = rsqrtf(s2q * (1.f / 64.f) - mq * mq + LNEPS) * qscale;

  bf16x8 ok, oq;
#pragma unroll
  for (int e = 0; e < 8; e++) {
    float gk = kg[lr * 8 + e], bk2 = kb[lr * 8 + e];
    float gq = qg[lr * 8 + e], bq2 = qb[lr * 8 + e];
    ok[e] = (bf16)(((fk[e] - mk) * rk) * gk + bk2 * kscale);
    oq[e] = (bf16)(((fq[e] - mq) * rq) * gq + bq2 * qscale);
  }
  const int b = tok >> 11, tt = tok & 2047;
  const size_t o = ((size_t)(b * HEADS + h) * SEQ + tt) * HD + lr * 8;
  *reinterpret_cast<bf16x8*>(kn + o) = ok;
  *reinterpret_cast<bf16x8*>(qn + o) = oq;
}

// ---------------- V transpose: [t][3072] (V at col 2048) -> [bh][64 d][2048 t] ----------------
__global__ void v_trans(const bf16* __restrict__ in, int ldin, bf16* __restrict__ out)
{
  __shared__ __align__(16) bf16 tile[64][72];
  int bh = blockIdx.y, jt = blockIdx.x;
  int b = bh >> 4, h = bh & 15;
  int t = threadIdx.x;
#pragma unroll
  for (int p = 0; p < 2; p++) {
    int rowj = p * 32 + (t >> 3);
    int cold = (t & 7) << 3;
    bf16x8 v = *reinterpret_cast<const bf16x8*>(
        &in[(size_t)(b * SEQ + jt * 64 + rowj) * ldin + h * HD + cold]);
    *reinterpret_cast<bf16x8*>(&tile[rowj][cold]) = v;
  }
  __syncthreads();
#pragma unroll
  for (int p = 0; p < 2; p++) {
    int rowd = p * 32 + (t >> 3);
    int colj = (t & 7) << 3;
    bf16x8 v;
#pragma unroll
    for (int jj = 0; jj < 8; jj++) v[jj] = tile[colj + jj][rowd];
    *reinterpret_cast<bf16x8*>(&out[((size_t)bh * HD + rowd) * SEQ + jt * 64 + colj]) = v;
  }
}

// ---------------- flash attention (causal), S^T form, paired tiles + dbuf ----------------
// Grid (16, 64 bh), 256 thr = 4 waves x 16 Q rows (QBLK=64). Pass 0: itile=bx,
// pass 1: itile=31-bx -> uniform 33 j-steps/block. j-tile 64, double-buffered
// K/V (32KB LDS, 4 blocks/CU), one barrier per tile, prefetch before compute.
// This round: ALL LDS-read addresses hoisted to loop-invariant per-lane byte
// offsets (rowj&7==ln&7, rowd&7==ln&7 since md*16/jb*16 = 0 mod 8):
//   K:  ko = ln*128 + ((q^(ln&7))<<4); second frag = ko^64; slab = +jb*2048 imm
//   V:  vo = ln*128 + (((q>>1)^(ln&7))<<4) + ((q&1)<<3); vo(jb)=vo^(jb<<5);
//       md folds as +md*2048 imm
// Staging uses running global pointers (+= const stride). s_setprio(1) wraps
// MFMA clusters (T5: attn-structured +4-7%, m191).
__global__ __launch_bounds__(256, 4) void attn(
    const bf16* __restrict__ Qn, const bf16* __restrict__ Kn, const bf16* __restrict__ Vt,
    bf16* __restrict__ O)
{
  __shared__ __align__(16) bf16 Ks[2][64 * 64];   // [j][d], 8192 B per buf
  __shared__ __align__(16) bf16 Vs[2][64 * 64];   // [d][j], 8192 B per buf

  const int bh = blockIdx.y;
  const int t = threadIdx.x, wave = t >> 6, lane = t & 63;
  const int q = lane >> 4, ln = lane & 15;
  const int b = bh >> 4, h = bh & 15;

  // staging source offsets (16B chunk per tensor per thread, x2)
  const int u0 = t * 8, u1 = t * 8 + 2048;
  const int kr0 = u0 >> 6, kc0 = ((u0 >> 3) & 7) ^ (kr0 & 7);
  const int kr1 = u1 >> 6, kc1 = ((u1 >> 3) & 7) ^ (kr1 & 7);
  const int vd0 = u0 >> 6, vc0 = ((u0 >> 3) & 7) ^ (vd0 & 7);
  const int vd1 = u1 >> 6, vc1 = ((u1 >> 3) & 7) ^ (vd1 & 7);
  const bf16* Kb = Kn + (size_t)bh * SEQ * HD;
  const bf16* Vb = Vt + (size_t)bh * HD * SEQ;

  // hoisted LDS read byte-offsets (loop-invariant per lane)
  const int ko  = ln * 128 + ((q ^ (ln & 7)) << 4);
  const int ko2 = ko ^ 64;
  const int vo0 = ln * 128 + ((((q >> 1)) ^ (ln & 7)) << 4) + ((q & 1) << 3);
  const int vo1 = vo0 ^ 32, vo2 = vo0 ^ 64, vo3 = vo0 ^ 96;
  const char* KsB = (const char*)&Ks[0][0];
  const char* VsB = (const char*)&Vs[0][0];

  f32x4 zero4 = {0.f, 0.f, 0.f, 0.f};

  for (int pass = 0; pass < 2; ++pass) {
    const int itile = pass ? (31 - (int)blockIdx.x) : (int)blockIdx.x;
    const int qbase = itile * 64 + wave * 16;

    // Q fragments (B-operand of S^T mfma): Q[i=qbase+ln][d=ks*32+q*8 ..+8]
    const bf16* qp = Qn + ((size_t)bh * SEQ + qbase + ln) * HD + q * 8;
    bf16x8 qf0 = *reinterpret_cast<const bf16x8*>(qp);
    bf16x8 qf1 = *reinterpret_cast<const bf16x8*>(qp + 32);

    float lrow = 0.f;
    f32x4 oacc[4];                          // [md] tiles of O^T[d][i]
#pragma unroll
    for (int md = 0; md < 4; md++) oacc[md] = zero4;

    const int nj = itile + 1;               // 64-j tiles covering 0..i0+63

    // running staging pointers (advance by const stride per tile)
    const bf16* pk0 = Kb + (size_t)kr0 * HD + kc0 * 8;
    const bf16* pk1 = Kb + (size_t)kr1 * HD + kc1 * 8;
    const bf16* pv0 = Vb + (size_t)vd0 * SEQ + vc0 * 8;
    const bf16* pv1 = Vb + (size_t)vd1 * SEQ + vc1 * 8;

    __syncthreads();                        // prior pass/iter reads done before overwrite
    {                                       // prologue: stage jt=0 into buf 0
      gld_lds16(pk0, &Ks[0][u0]);
      gld_lds16(pk1, &Ks[0][u1]);
      gld_lds16(pv0, &Vs[0][u0]);
      gld_lds16(pv1, &Vs[0][u1]);
      pk0 += 64 * HD; pk1 += 64 * HD; pv0 += 64; pv1 += 64;
    }

    for (int jt = 0; jt < nj; ++jt) {
      const int buf = jt & 1;
      const int bo = buf << 13;             // byte offset of current buffer
      __syncthreads();                      // buf staged & visible; buf^1 reads drained
      if (jt + 1 < nj) {                    // prefetch next tile into other buffer
        gld_lds16(pk0, &Ks[buf ^ 1][u0]);
        gld_lds16(pk1, &Ks[buf ^ 1][u1]);
        gld_lds16(pv0, &Vs[buf ^ 1][u0]);
        gld_lds16(pv1, &Vs[buf ^ 1][u1]);
        pk0 += 64 * HD; pk1 += 64 * HD; pv0 += 64; pv1 += 64;
      }

      const char* kb0 = KsB + bo + ko;      // per-tile LDS read bases
      const char* kb1 = KsB + bo + ko2;
      const char* vbA = VsB + bo + vo0;
      const char* vbB = VsB + bo + vo1;
      const char* vbC = VsB + bo + vo2;
      const char* vbD = VsB + bo + vo3;
      const int j0 = jt * 64;

#pragma unroll
      for (int jb = 0; jb < 4; ++jb) {
        const int jslab = j0 + jb * 16;
        if (jslab <= qbase + 15) {          // slab has unmasked elems for this wave
          bf16x8 kf0 = *reinterpret_cast<const bf16x8*>(kb0 + jb * 2048);
          bf16x8 kf1 = *reinterpret_cast<const bf16x8*>(kb1 + jb * 2048);
          f32x4 z = zero4;
          __builtin_amdgcn_s_setprio(1);
          z = __builtin_amdgcn_mfma_f32_16x16x32_bf16(kf0, qf0, z, 0, 0, 0);
          z = __builtin_amdgcn_mfma_f32_16x16x32_bf16(kf1, qf1, z, 0, 0, 0);
          __builtin_amdgcn_s_setprio(0);
          // z[r] = S^T[j = jslab+q*4+r][i = qbase+ln]
          if (jslab + 15 > qbase) {         // partial slab: mask
#pragma unroll
            for (int r = 0; r < 4; r++) {
              int jj = jslab + q * 4 + r;
              int ii = qbase + ln;
              if (jj > ii) z[r] = -1.0e30f;
            }
          }
          // fixed-max softmax (|s*log2e| <= 2.9 after per-head LN): p = 2^s
          float p0 = exp2f(z[0]), p1 = exp2f(z[1]), p2 = exp2f(z[2]), p3 = exp2f(z[3]);
          lrow += (p0 + p1) + (p2 + p3);
          bf16x4 pk = { (bf16)p0, (bf16)p1, (bf16)p2, (bf16)p3 };   // B-frag (k=j, n=i)

          // O^T += V^T * P^T for this 16-j slab; V frag addr = vb? ^ hoisted,
          // md as immediate offset
          const char* vbase = (jb == 0) ? vbA : (jb == 1) ? vbB : (jb == 2) ? vbC : vbD;
          __builtin_amdgcn_s_setprio(1);
#pragma unroll
          for (int md = 0; md < 4; md++) {
            bf16x4 vf = *reinterpret_cast<const bf16x4*>(vbase + md * 2048);
            oacc[md] = mfma_pv(vf, pk, oacc[md]);
          }
          __builtin_amdgcn_s_setprio(0);
        }
      }
    }

    // epilogue: reduce l over the 4 quads holding each column i, normalize, store
    float s = lrow;
    s += __shfl_xor(s, 16, 64);
    s += __shfl_xor(s, 32, 64);
    const float inv = 1.f / s;
    const int row = qbase + ln;
#pragma unroll
    for (int md = 0; md < 4; md++) {
      bf16x4 o4 = { (bf16)(oacc[md][0] * inv), (bf16)(oacc[md][1] * inv),
                    (bf16)(oacc[md][2] * inv), (bf16)(oacc[md][3] * inv) };
      int col = h * HD + md * 16 + q * 4;    // 4 consecutive d
      *reinterpret_cast<bf16x4*>(&O[(size_t)(b * SEQ + row) * EMB + col]) = o4;
    }
  }
}

// ---------------- launch ----------------
extern "C" void kernel_launch(void* const* d_in, const int* in_sizes, int n_in,
                              void* d_out, int out_size, void* d_ws, size_t ws_size,
                              hipStream_t stream)
{
  const float* x   = (const float*)d_in[0];
  const float* Wk  = (const float*)d_in[1];
  const float* Wq  = (const float*)d_in[2];
  const float* Wv  = (const float*)d_in[3];
  const float* Wo  = (const float*)d_in[4];
  const float* bo  = (const float*)d_in[5];
  const float* klg = (const float*)d_in[6];
  const float* klb = (const float*)d_in[7];
  const float* qlg = (const float*)d_in[8];
  const float* qlb = (const float*)d_in[9];
  float* out = (float*)d_out;

  char* ws = (char*)d_ws;
  const size_t OFF_XB  = 0;
  const size_t OFF_WB  = OFF_XB  + (size_t)BT * EMB * 2;
  const size_t OFF_KQV = OFF_WB  + (size_t)4 * EMB * EMB * 2;
  const size_t OFF_KN  = OFF_KQV + (size_t)BT * 3 * EMB * 2;
  const size_t OFF_QN  = OFF_KN  + (size_t)BT * EMB * 2;
  const size_t OFF_VT  = OFF_QN  + (size_t)BT * EMB * 2;
  const size_t OFF_END = OFF_VT  + (size_t)BT * EMB * 2;
  if (ws_size < OFF_END) return;

  bf16* xb   = (bf16*)(ws + OFF_XB);
  bf16* wb   = (bf16*)(ws + OFF_WB);
  bf16* kqv  = (bf16*)(ws + OFF_KQV);
  bf16* kn   = (bf16*)(ws + OFF_KN);
  bf16* qn   = (bf16*)(ws + OFF_QN);
  bf16* vt   = (bf16*)(ws + OFF_VT);
  bf16* ob   = (bf16*)(ws + OFF_KQV);    // alias: KQV dead after ln/v_trans

  cvt_f32_bf16<<<(BT * EMB / 4) / 256, 256, 0, stream>>>(x, xb, BT * EMB / 4);
  cvt_w4<<<(4 * EMB * EMB / 4) / 256, 256, 0, stream>>>(Wk, Wq, Wv, Wo, wb);

  gemm_bt<0><<<dim3(3 * EMB / 128, BT / 128), 256, 0, stream>>>(
      xb, wb, kqv, (float*)nullptr, (const float*)nullptr, BT, 3 * EMB, EMB);

  ln_kq<<<BT * HEADS / 32, 256, 0, stream>>>(kqv, kn, qn, klg, klb, qlg, qlb,
                                             QK_SCALE * LOG2E, QK_SCALE);
  v_trans<<<dim3(SEQ / 64, BATCH * HEADS), 256, 0, stream>>>(kqv + 2 * EMB, 3 * EMB, vt);

  attn<<<dim3(16, BATCH * HEADS), 256, 0, stream>>>(qn, kn, vt, ob);

  gemm_bt<1><<<dim3(EMB / 128, BT / 128), 256, 0, stream>>>(
      ob, wb + (size_t)3 * EMB * EMB, (bf16*)nullptr, out, bo, BT, EMB, EMB);
}

// Round 4
// 291.516 us; speedup vs baseline: 1.0429x; 1.0429x over previous
//
#include <hip/hip_runtime.h>
#include <hip/hip_bf16.h>
#include <cstdint>

#define EMB 1024
#define HEADS 16
#define HD 64
#define BATCH 4
#define SEQ 2048
#define BT (BATCH*SEQ)                 // 8192 tokens
#define LNEPS 1e-5f
#define QK_SCALE 0.17677669529663687f  // 1024^-0.25
#define LOG2E 1.4426950408889634f

typedef __bf16 bf16;
typedef __bf16 bf16x8 __attribute__((ext_vector_type(8)));
typedef __bf16 bf16x4 __attribute__((ext_vector_type(4)));
typedef float  f32x4  __attribute__((ext_vector_type(4)));
typedef short  s16x4  __attribute__((ext_vector_type(4)));

typedef const __attribute__((address_space(1))) void* gas_ptr;
typedef __attribute__((address_space(3))) void*       las_ptr;

__device__ __forceinline__ void gld_lds16(const void* g, void* l) {
  __builtin_amdgcn_global_load_lds((gas_ptr)g, (las_ptr)l, 16, 0, 0);
}

// PV matmul: 16x16x16 bf16 MFMA (C-layout of S^T == B-layout of this shape).
__device__ __forceinline__ f32x4 mfma_pv(bf16x4 a, bf16x4 b, f32x4 c) {
  return __builtin_amdgcn_mfma_f32_16x16x16bf16_1k(
      __builtin_bit_cast(s16x4, a), __builtin_bit_cast(s16x4, b), c, 0, 0, 0);
}

// ---------------- fp32 -> bf16 conversion ----------------
__global__ void cvt_f32_bf16(const float* __restrict__ src, bf16* __restrict__ dst, int n4) {
  int i = blockIdx.x * blockDim.x + threadIdx.x;
  if (i >= n4) return;
  float4 f = reinterpret_cast<const float4*>(src)[i];
  bf16x4 o = { (bf16)f.x, (bf16)f.y, (bf16)f.z, (bf16)f.w };
  reinterpret_cast<bf16x4*>(dst)[i] = o;
}

// 4 weight matrices (1024x1024 each) -> contiguous bf16 [4*1024][1024]
__global__ void cvt_w4(const float* __restrict__ w0, const float* __restrict__ w1,
                       const float* __restrict__ w2, const float* __restrict__ w3,
                       bf16* __restrict__ dst) {
  int i = blockIdx.x * blockDim.x + threadIdx.x;   // over 4*262144 float4s
  int sel = i >> 18;
  int j = i & 262143;
  const float* s = (sel == 0) ? w0 : (sel == 1) ? w1 : (sel == 2) ? w2 : w3;
  float4 f = reinterpret_cast<const float4*>(s)[j];
  bf16x4 o = { (bf16)f.x, (bf16)f.y, (bf16)f.z, (bf16)f.w };
  reinterpret_cast<bf16x4*>(dst)[i] = o;
}

// ---------------- m97-style GEMM: C[M][N] = A[M][K] * B[N][K]^T ----------------
template<int OUTF32>
__global__ __launch_bounds__(256, 2) void gemm_bt(
    const bf16* __restrict__ A, const bf16* __restrict__ Bm,
    bf16* __restrict__ Cb, float* __restrict__ Cf, const float* __restrict__ bias,
    int M, int N, int K)
{
  __shared__ __align__(16) bf16 As[128 * 32];
  __shared__ __align__(16) bf16 Bs[128 * 32];

  const int t    = threadIdx.x;
  const int lane = t & 63;
  const int wave = t >> 6;
  const int q    = lane >> 4;
  const int ln   = lane & 15;
  const int m0   = blockIdx.y * 128;
  const int n0   = blockIdx.x * 128;
  const int wm   = (wave >> 1) * 64;
  const int wn   = (wave & 1) * 64;

  const int r0 = t >> 2;
  const int c0 = (t & 3) << 3;

  f32x4 zero4 = {0.f, 0.f, 0.f, 0.f};
  f32x4 acc[4][4];
#pragma unroll
  for (int i = 0; i < 4; i++)
#pragma unroll
    for (int j = 0; j < 4; j++) acc[i][j] = zero4;

  for (int k0 = 0; k0 < K; k0 += 32) {
    __syncthreads();
    const bf16* ga = A  + (size_t)(m0 + r0) * K + k0 + c0;
    const bf16* gb = Bm + (size_t)(n0 + r0) * K + k0 + c0;
    gld_lds16(ga,                  &As[t * 8]);
    gld_lds16(ga + (size_t)64 * K, &As[t * 8 + 2048]);
    gld_lds16(gb,                  &Bs[t * 8]);
    gld_lds16(gb + (size_t)64 * K, &Bs[t * 8 + 2048]);
    __syncthreads();

    bf16x8 af[4], bfr[4];
#pragma unroll
    for (int mi = 0; mi < 4; mi++)
      af[mi] = *reinterpret_cast<const bf16x8*>(&As[(wm + mi * 16 + ln) * 32 + q * 8]);
#pragma unroll
    for (int ni = 0; ni < 4; ni++)
      bfr[ni] = *reinterpret_cast<const bf16x8*>(&Bs[(wn + ni * 16 + ln) * 32 + q * 8]);
#pragma unroll
    for (int mi = 0; mi < 4; mi++)
#pragma unroll
      for (int ni = 0; ni < 4; ni++)
        acc[mi][ni] = __builtin_amdgcn_mfma_f32_16x16x32_bf16(af[mi], bfr[ni], acc[mi][ni], 0, 0, 0);
  }

#pragma unroll
  for (int mi = 0; mi < 4; mi++) {
#pragma unroll
    for (int ni = 0; ni < 4; ni++) {
#pragma unroll
      for (int r = 0; r < 4; r++) {
        int row = m0 + wm + mi * 16 + q * 4 + r;
        int col = n0 + wn + ni * 16 + ln;
        float v = acc[mi][ni][r];
        if (OUTF32) Cf[(size_t)row * N + col] = v + bias[col];
        else        Cb[(size_t)row * N + col] = (bf16)v;
      }
    }
  }
}

// ---------------- per-head LayerNorm for K and Q, vectorized ----------------
// kqv: [8192][3072]; K at col 0, Q at col 1024. Outputs [bh][t][64].
// 8 lanes per row, bf16x8 loads/stores. kscale includes log2(e).
__global__ void ln_kq(const bf16* __restrict__ kqv,
                      bf16* __restrict__ kn, bf16* __restrict__ qn,
                      const float* __restrict__ kg, const float* __restrict__ kb,
                      const float* __restrict__ qg, const float* __restrict__ qb,
                      float kscale, float qscale)
{
  const int t = threadIdx.x;
  const int lr = t & 7;                       // lane within row
  const int row = blockIdx.x * 32 + (t >> 3); // row = tok*16 + h
  const int tok = row >> 4, h = row & 15;
  const size_t base = (size_t)tok * (3 * EMB) + h * HD + lr * 8;

  bf16x8 vk = *reinterpret_cast<const bf16x8*>(kqv + base);
  bf16x8 vq = *reinterpret_cast<const bf16x8*>(kqv + base + EMB);

  float fk[8], fq[8];
  float sk = 0.f, sq = 0.f, s2k = 0.f, s2q = 0.f;
#pragma unroll
  for (int e = 0; e < 8; e++) {
    fk[e] = (float)vk[e]; fq[e] = (float)vq[e];
    sk += fk[e]; sq += fq[e];
    s2k += fk[e] * fk[e]; s2q += fq[e] * fq[e];
  }
#pragma unroll
  for (int m = 1; m < 8; m <<= 1) {
    sk  += __shfl_xor(sk,  m, 64); sq  += __shfl_xor(sq,  m, 64);
    s2k += __shfl_xor(s2k, m, 64); s2q += __shfl_xor(s2q, m, 64);
  }
  float mk = sk * (1.f / 64.f), mq = sq * (1.f / 64.f);
  float rk = rsqrtf(s2k * (1.f / 64.f) - mk * mk + LNEPS) * kscale;
  float rq = rsqrtf(s2q * (1.f / 64.f) - mq * mq + LNEPS) * qscale;

  bf16x8 ok, oq;
#pragma unroll
  for (int e = 0; e < 8; e++) {
    float gk = kg[lr * 8 + e], bk2 = kb[lr * 8 + e];
    float gq = qg[lr * 8 + e], bq2 = qb[lr * 8 + e];
    ok[e] = (bf16)(((fk[e] - mk) * rk) * gk + bk2 * kscale);
    oq[e] = (bf16)(((fq[e] - mq) * rq) * gq + bq2 * qscale);
  }
  const int b = tok >> 11, tt = tok & 2047;
  const size_t o = ((size_t)(b * HEADS + h) * SEQ + tt) * HD + lr * 8;
  *reinterpret_cast<bf16x8*>(kn + o) = ok;
  *reinterpret_cast<bf16x8*>(qn + o) = oq;
}

// ---------------- V transpose: [t][3072] (V at col 2048) -> [bh][64 d][2048 t] ----------------
__global__ void v_trans(const bf16* __restrict__ in, int ldin, bf16* __restrict__ out)
{
  __shared__ __align__(16) bf16 tile[64][72];
  int bh = blockIdx.y, jt = blockIdx.x;
  int b = bh >> 4, h = bh & 15;
  int t = threadIdx.x;
#pragma unroll
  for (int p = 0; p < 2; p++) {
    int rowj = p * 32 + (t >> 3);
    int cold = (t & 7) << 3;
    bf16x8 v = *reinterpret_cast<const bf16x8*>(
        &in[(size_t)(b * SEQ + jt * 64 + rowj) * ldin + h * HD + cold]);
    *reinterpret_cast<bf16x8*>(&tile[rowj][cold]) = v;
  }
  __syncthreads();
#pragma unroll
  for (int p = 0; p < 2; p++) {
    int rowd = p * 32 + (t >> 3);
    int colj = (t & 7) << 3;
    bf16x8 v;
#pragma unroll
    for (int jj = 0; jj < 8; jj++) v[jj] = tile[colj + jj][rowd];
    *reinterpret_cast<bf16x8*>(&out[((size_t)bh * HD + rowd) * SEQ + jt * 64 + colj]) = v;
  }
}

// ---------------- flash attention (causal), S^T form, paired tiles + dbuf ----------------
// 1-D grid of 1024 blocks, XCD-affine decode: xcd=id&7, bx=(id>>3)&15,
// bh=(id>>7)*8+xcd. With round-robin id%8 -> XCD dispatch, ALL 16 blocks of a
// bh land on ONE XCD (128 blocks = 32 CU x 4 blocks/CU resident per XCD), and
// that XCD's L2 (4MB) holds its 8 bhs' K/V (8 x 512KB) exactly. In pass 0 the
// 16 blocks of a bh stream the SAME j-tile in lockstep -> K/V fetched from HBM
// ~once. Prev layout spread each bh over all 8 XCDs: FETCH 255MB ~= 64bh x
// 8XCD x 512KB. Pass pairing (bx then 31-bx) keeps 33 j-steps per block.
// j-tile 64, double-buffered K/V (32KB LDS, 4 blocks/CU), one barrier per
// tile, prefetch issued before compute. Swizzles: 16B-chunk XOR (row&7),
// both-sides involution -> 2-way max on reads (free).
__global__ __launch_bounds__(256, 4) void attn(
    const bf16* __restrict__ Qn, const bf16* __restrict__ Kn, const bf16* __restrict__ Vt,
    bf16* __restrict__ O)
{
  __shared__ __align__(16) bf16 Ks[2][64 * 64];   // [j][d]
  __shared__ __align__(16) bf16 Vs[2][64 * 64];   // [d][j]

  const int id = blockIdx.x;
  const int bh = ((id >> 7) << 3) | (id & 7);     // same-bh blocks share an XCD
  const int bxi = (id >> 3) & 15;
  const int t = threadIdx.x, wave = t >> 6, lane = t & 63;
  const int q = lane >> 4, ln = lane & 15;
  const int b = bh >> 4, h = bh & 15;

  // staging: 2 chunks of 16B per tensor per thread (u0, u0+2048 elems)
  const int u0 = t * 8, u1 = t * 8 + 2048;
  const int kr0 = u0 >> 6, kc0 = ((u0 >> 3) & 7) ^ (kr0 & 7);
  const int kr1 = u1 >> 6, kc1 = ((u1 >> 3) & 7) ^ (kr1 & 7);
  const int vd0 = u0 >> 6, vc0 = ((u0 >> 3) & 7) ^ (vd0 & 7);
  const int vd1 = u1 >> 6, vc1 = ((u1 >> 3) & 7) ^ (vd1 & 7);
  const bf16* Kb = Kn + (size_t)bh * SEQ * HD;
  const bf16* Vb = Vt + (size_t)bh * HD * SEQ;

  f32x4 zero4 = {0.f, 0.f, 0.f, 0.f};

  for (int pass = 0; pass < 2; ++pass) {
    const int itile = pass ? (31 - bxi) : bxi;
    const int qbase = itile * 64 + wave * 16;

    // Q fragments (B-operand of S^T mfma): Q[i=qbase+ln][d=ks*32+q*8 ..+8]
    const bf16* qp = Qn + ((size_t)bh * SEQ + qbase + ln) * HD + q * 8;
    bf16x8 qf0 = *reinterpret_cast<const bf16x8*>(qp);
    bf16x8 qf1 = *reinterpret_cast<const bf16x8*>(qp + 32);

    float lrow = 0.f;
    f32x4 oacc[4];                          // [md] tiles of O^T[d][i]
#pragma unroll
    for (int md = 0; md < 4; md++) oacc[md] = zero4;

    const int nj = itile + 1;               // 64-j tiles covering 0..i0+63

    __syncthreads();                        // prior pass/iter reads done before overwrite
    {                                       // prologue: stage jt=0 into buf 0
      gld_lds16(Kb + (size_t)kr0 * HD + kc0 * 8, &Ks[0][u0]);
      gld_lds16(Kb + (size_t)kr1 * HD + kc1 * 8, &Ks[0][u1]);
      gld_lds16(Vb + (size_t)vd0 * SEQ + vc0 * 8, &Vs[0][u0]);
      gld_lds16(Vb + (size_t)vd1 * SEQ + vc1 * 8, &Vs[0][u1]);
    }

    for (int jt = 0; jt < nj; ++jt) {
      const int buf = jt & 1;
      const int j0 = jt * 64;
      __syncthreads();                      // buf staged & visible; buf^1 reads drained
      if (jt + 1 < nj) {                    // prefetch next tile into other buffer
        const int jn = j0 + 64;
        gld_lds16(Kb + (size_t)(jn + kr0) * HD + kc0 * 8, &Ks[buf ^ 1][u0]);
        gld_lds16(Kb + (size_t)(jn + kr1) * HD + kc1 * 8, &Ks[buf ^ 1][u1]);
        gld_lds16(Vb + (size_t)vd0 * SEQ + jn + vc0 * 8, &Vs[buf ^ 1][u0]);
        gld_lds16(Vb + (size_t)vd1 * SEQ + jn + vc1 * 8, &Vs[buf ^ 1][u1]);
      }

#pragma unroll
      for (int jb = 0; jb < 4; ++jb) {
        const int jslab = j0 + jb * 16;
        if (jslab <= qbase + 15) {          // slab has unmasked elems for this wave
          const int rowj = jb * 16 + ln;
          bf16x8 kf0 = *reinterpret_cast<const bf16x8*>(
              &Ks[buf][rowj * 64 + ((q)     ^ (rowj & 7)) * 8]);
          bf16x8 kf1 = *reinterpret_cast<const bf16x8*>(
              &Ks[buf][rowj * 64 + ((4 + q) ^ (rowj & 7)) * 8]);
          f32x4 z = zero4;
          z = __builtin_amdgcn_mfma_f32_16x16x32_bf16(kf0, qf0, z, 0, 0, 0);
          z = __builtin_amdgcn_mfma_f32_16x16x32_bf16(kf1, qf1, z, 0, 0, 0);
          // z[r] = S^T[j = jslab+q*4+r][i = qbase+ln]
          if (jslab + 15 > qbase) {         // partial slab: mask
#pragma unroll
            for (int r = 0; r < 4; r++) {
              int jj = jslab + q * 4 + r;
              int ii = qbase + ln;
              if (jj > ii) z[r] = -1.0e30f;
            }
          }
          // fixed-max softmax (|s*log2e| <= 2.9 after per-head LN): p = 2^s
          float p0 = exp2f(z[0]), p1 = exp2f(z[1]), p2 = exp2f(z[2]), p3 = exp2f(z[3]);
          lrow += (p0 + p1) + (p2 + p3);
          bf16x4 pk = { (bf16)p0, (bf16)p1, (bf16)p2, (bf16)p3 };   // B-frag (k=j, n=i)

          // O^T += V^T * P^T for this 16-j slab
#pragma unroll
          for (int md = 0; md < 4; md++) {
            const int rowd = md * 16 + ln;
            const bf16* vp = &Vs[buf][rowd * 64 +
                (((jb * 2 + (q >> 1)) ^ (rowd & 7)) * 8) + (q & 1) * 4];
            bf16x4 vf = *reinterpret_cast<const bf16x4*>(vp);
            oacc[md] = mfma_pv(vf, pk, oacc[md]);
          }
        }
      }
    }

    // epilogue: reduce l over the 4 quads holding each column i, normalize, store
    float s = lrow;
    s += __shfl_xor(s, 16, 64);
    s += __shfl_xor(s, 32, 64);
    const float inv = 1.f / s;
    const int row = qbase + ln;
#pragma unroll
    for (int md = 0; md < 4; md++) {
      bf16x4 o4 = { (bf16)(oacc[md][0] * inv), (bf16)(oacc[md][1] * inv),
                    (bf16)(oacc[md][2] * inv), (bf16)(oacc[md][3] * inv) };
      int col = h * HD + md * 16 + q * 4;    // 4 consecutive d
      *reinterpret_cast<bf16x4*>(&O[(size_t)(b * SEQ + row) * EMB + col]) = o4;
    }
  }
}

// ---------------- launch ----------------
extern "C" void kernel_launch(void* const* d_in, const int* in_sizes, int n_in,
                              void* d_out, int out_size, void* d_ws, size_t ws_size,
                              hipStream_t stream)
{
  const float* x   = (const float*)d_in[0];
  const float* Wk  = (const float*)d_in[1];
  const float* Wq  = (const float*)d_in[2];
  const float* Wv  = (const float*)d_in[3];
  const float* Wo  = (const float*)d_in[4];
  const float* bo  = (const float*)d_in[5];
  const float* klg = (const float*)d_in[6];
  const float* klb = (const float*)d_in[7];
  const float* qlg = (const float*)d_in[8];
  const float* qlb = (const float*)d_in[9];
  float* out = (float*)d_out;

  char* ws = (char*)d_ws;
  const size_t OFF_XB  = 0;
  const size_t OFF_WB  = OFF_XB  + (size_t)BT * EMB * 2;
  const size_t OFF_KQV = OFF_WB  + (size_t)4 * EMB * EMB * 2;
  const size_t OFF_KN  = OFF_KQV + (size_t)BT * 3 * EMB * 2;
  const size_t OFF_QN  = OFF_KN  + (size_t)BT * EMB * 2;
  const size_t OFF_VT  = OFF_QN  + (size_t)BT * EMB * 2;
  const size_t OFF_END = OFF_VT  + (size_t)BT * EMB * 2;
  if (ws_size < OFF_END) return;

  bf16* xb   = (bf16*)(ws + OFF_XB);
  bf16* wb   = (bf16*)(ws + OFF_WB);
  bf16* kqv  = (bf16*)(ws + OFF_KQV);
  bf16* kn   = (bf16*)(ws + OFF_KN);
  bf16* qn   = (bf16*)(ws + OFF_QN);
  bf16* vt   = (bf16*)(ws + OFF_VT);
  bf16* ob   = (bf16*)(ws + OFF_KQV);    // alias: KQV dead after ln/v_trans

  cvt_f32_bf16<<<(BT * EMB / 4) / 256, 256, 0, stream>>>(x, xb, BT * EMB / 4);
  cvt_w4<<<(4 * EMB * EMB / 4) / 256, 256, 0, stream>>>(Wk, Wq, Wv, Wo, wb);

  gemm_bt<0><<<dim3(3 * EMB / 128, BT / 128), 256, 0, stream>>>(
      xb, wb, kqv, (float*)nullptr, (const float*)nullptr, BT, 3 * EMB, EMB);

  ln_kq<<<BT * HEADS / 32, 256, 0, stream>>>(kqv, kn, qn, klg, klb, qlg, qlb,
                                             QK_SCALE * LOG2E, QK_SCALE);
  v_trans<<<dim3(SEQ / 64, BATCH * HEADS), 256, 0, stream>>>(kqv + 2 * EMB, 3 * EMB, vt);

  attn<<<dim3(16 * BATCH * HEADS), 256, 0, stream>>>(qn, kn, vt, ob);

  gemm_bt<1><<<dim3(EMB / 128, BT / 128), 256, 0, stream>>>(
      ob, wb + (size_t)3 * EMB * EMB, (bf16*)nullptr, out, bo, BT, EMB, EMB);
}

// Round 5
// 288.947 us; speedup vs baseline: 1.0521x; 1.0089x over previous
//
#include <hip/hip_runtime.h>
#include <hip/hip_bf16.h>
#include <cstdint>

#define EMB 1024
#define HEADS 16
#define HD 64
#define BATCH 4
#define SEQ 2048
#define BT (BATCH*SEQ)                 // 8192 tokens
#define LNEPS 1e-5f
#define QK_SCALE 0.17677669529663687f  // 1024^-0.25
#define LOG2E 1.4426950408889634f

typedef __bf16 bf16;
typedef __bf16 bf16x8 __attribute__((ext_vector_type(8)));
typedef __bf16 bf16x4 __attribute__((ext_vector_type(4)));
typedef float  f32x4  __attribute__((ext_vector_type(4)));
typedef short  s16x4  __attribute__((ext_vector_type(4)));

typedef const __attribute__((address_space(1))) void* gas_ptr;
typedef __attribute__((address_space(3))) void*       las_ptr;

__device__ __forceinline__ void gld_lds16(const void* g, void* l) {
  __builtin_amdgcn_global_load_lds((gas_ptr)g, (las_ptr)l, 16, 0, 0);
}

// PV matmul: 16x16x16 bf16 MFMA (C-layout of S^T == B-layout of this shape).
__device__ __forceinline__ f32x4 mfma_pv(bf16x4 a, bf16x4 b, f32x4 c) {
  return __builtin_amdgcn_mfma_f32_16x16x16bf16_1k(
      __builtin_bit_cast(s16x4, a), __builtin_bit_cast(s16x4, b), c, 0, 0, 0);
}

// ---------------- fp32 -> bf16 conversion ----------------
__global__ void cvt_f32_bf16(const float* __restrict__ src, bf16* __restrict__ dst, int n4) {
  int i = blockIdx.x * blockDim.x + threadIdx.x;
  if (i >= n4) return;
  float4 f = reinterpret_cast<const float4*>(src)[i];
  bf16x4 o = { (bf16)f.x, (bf16)f.y, (bf16)f.z, (bf16)f.w };
  reinterpret_cast<bf16x4*>(dst)[i] = o;
}

// 4 weight matrices (1024x1024 each) -> contiguous bf16 [4*1024][1024]
__global__ void cvt_w4(const float* __restrict__ w0, const float* __restrict__ w1,
                       const float* __restrict__ w2, const float* __restrict__ w3,
                       bf16* __restrict__ dst) {
  int i = blockIdx.x * blockDim.x + threadIdx.x;   // over 4*262144 float4s
  int sel = i >> 18;
  int j = i & 262143;
  const float* s = (sel == 0) ? w0 : (sel == 1) ? w1 : (sel == 2) ? w2 : w3;
  float4 f = reinterpret_cast<const float4*>(s)[j];
  bf16x4 o = { (bf16)f.x, (bf16)f.y, (bf16)f.z, (bf16)f.w };
  reinterpret_cast<bf16x4*>(dst)[i] = o;
}

// ---------------- m97-style GEMM: C[M][N] = A[M][K] * B[N][K]^T ----------------
template<int OUTF32>
__global__ __launch_bounds__(256, 2) void gemm_bt(
    const bf16* __restrict__ A, const bf16* __restrict__ Bm,
    bf16* __restrict__ Cb, float* __restrict__ Cf, const float* __restrict__ bias,
    int M, int N, int K)
{
  __shared__ __align__(16) bf16 As[128 * 32];
  __shared__ __align__(16) bf16 Bs[128 * 32];

  const int t    = threadIdx.x;
  const int lane = t & 63;
  const int wave = t >> 6;
  const int q    = lane >> 4;
  const int ln   = lane & 15;
  const int m0   = blockIdx.y * 128;
  const int n0   = blockIdx.x * 128;
  const int wm   = (wave >> 1) * 64;
  const int wn   = (wave & 1) * 64;

  const int r0 = t >> 2;
  const int c0 = (t & 3) << 3;

  f32x4 zero4 = {0.f, 0.f, 0.f, 0.f};
  f32x4 acc[4][4];
#pragma unroll
  for (int i = 0; i < 4; i++)
#pragma unroll
    for (int j = 0; j < 4; j++) acc[i][j] = zero4;

  for (int k0 = 0; k0 < K; k0 += 32) {
    __syncthreads();
    const bf16* ga = A  + (size_t)(m0 + r0) * K + k0 + c0;
    const bf16* gb = Bm + (size_t)(n0 + r0) * K + k0 + c0;
    gld_lds16(ga,                  &As[t * 8]);
    gld_lds16(ga + (size_t)64 * K, &As[t * 8 + 2048]);
    gld_lds16(gb,                  &Bs[t * 8]);
    gld_lds16(gb + (size_t)64 * K, &Bs[t * 8 + 2048]);
    __syncthreads();

    bf16x8 af[4], bfr[4];
#pragma unroll
    for (int mi = 0; mi < 4; mi++)
      af[mi] = *reinterpret_cast<const bf16x8*>(&As[(wm + mi * 16 + ln) * 32 + q * 8]);
#pragma unroll
    for (int ni = 0; ni < 4; ni++)
      bfr[ni] = *reinterpret_cast<const bf16x8*>(&Bs[(wn + ni * 16 + ln) * 32 + q * 8]);
#pragma unroll
    for (int mi = 0; mi < 4; mi++)
#pragma unroll
      for (int ni = 0; ni < 4; ni++)
        acc[mi][ni] = __builtin_amdgcn_mfma_f32_16x16x32_bf16(af[mi], bfr[ni], acc[mi][ni], 0, 0, 0);
  }

#pragma unroll
  for (int mi = 0; mi < 4; mi++) {
#pragma unroll
    for (int ni = 0; ni < 4; ni++) {
#pragma unroll
      for (int r = 0; r < 4; r++) {
        int row = m0 + wm + mi * 16 + q * 4 + r;
        int col = n0 + wn + ni * 16 + ln;
        float v = acc[mi][ni][r];
        if (OUTF32) Cf[(size_t)row * N + col] = v + bias[col];
        else        Cb[(size_t)row * N + col] = (bf16)v;
      }
    }
  }
}

// ---------------- per-head LayerNorm for K and Q, vectorized ----------------
// kqv: [8192][3072]; K at col 0, Q at col 1024. Outputs [bh][t][64].
// 8 lanes per row, bf16x8 loads/stores. kscale includes log2(e).
__global__ void ln_kq(const bf16* __restrict__ kqv,
                      bf16* __restrict__ kn, bf16* __restrict__ qn,
                      const float* __restrict__ kg, const float* __restrict__ kb,
                      const float* __restrict__ qg, const float* __restrict__ qb,
                      float kscale, float qscale)
{
  const int t = threadIdx.x;
  const int lr = t & 7;                       // lane within row
  const int row = blockIdx.x * 32 + (t >> 3); // row = tok*16 + h
  const int tok = row >> 4, h = row & 15;
  const size_t base = (size_t)tok * (3 * EMB) + h * HD + lr * 8;

  bf16x8 vk = *reinterpret_cast<const bf16x8*>(kqv + base);
  bf16x8 vq = *reinterpret_cast<const bf16x8*>(kqv + base + EMB);

  float fk[8], fq[8];
  float sk = 0.f, sq = 0.f, s2k = 0.f, s2q = 0.f;
#pragma unroll
  for (int e = 0; e < 8; e++) {
    fk[e] = (float)vk[e]; fq[e] = (float)vq[e];
    sk += fk[e]; sq += fq[e];
    s2k += fk[e] * fk[e]; s2q += fq[e] * fq[e];
  }
#pragma unroll
  for (int m = 1; m < 8; m <<= 1) {
    sk  += __shfl_xor(sk,  m, 64); sq  += __shfl_xor(sq,  m, 64);
    s2k += __shfl_xor(s2k, m, 64); s2q += __shfl_xor(s2q, m, 64);
  }
  float mk = sk * (1.f / 64.f), mq = sq * (1.f / 64.f);
  float rk = rsqrtf(s2k * (1.f / 64.f) - mk * mk + LNEPS) * kscale;
  float rq = rsqrtf(s2q * (1.f / 64.f) - mq * mq + LNEPS) * qscale;

  bf16x8 ok, oq;
#pragma unroll
  for (int e = 0; e < 8; e++) {
    float gk = kg[lr * 8 + e], bk2 = kb[lr * 8 + e];
    float gq = qg[lr * 8 + e], bq2 = qb[lr * 8 + e];
    ok[e] = (bf16)(((fk[e] - mk) * rk) * gk + bk2 * kscale);
    oq[e] = (bf16)(((fq[e] - mq) * rq) * gq + bq2 * qscale);
  }
  const int b = tok >> 11, tt = tok & 2047;
  const size_t o = ((size_t)(b * HEADS + h) * SEQ + tt) * HD + lr * 8;
  *reinterpret_cast<bf16x8*>(kn + o) = ok;
  *reinterpret_cast<bf16x8*>(qn + o) = oq;
}

// ---------------- V transpose: [t][3072] (V at col 2048) -> [bh][64 d][2048 t] ----------------
__global__ void v_trans(const bf16* __restrict__ in, int ldin, bf16* __restrict__ out)
{
  __shared__ __align__(16) bf16 tile[64][72];
  int bh = blockIdx.y, jt = blockIdx.x;
  int b = bh >> 4, h = bh & 15;
  int t = threadIdx.x;
#pragma unroll
  for (int p = 0; p < 2; p++) {
    int rowj = p * 32 + (t >> 3);
    int cold = (t & 7) << 3;
    bf16x8 v = *reinterpret_cast<const bf16x8*>(
        &in[(size_t)(b * SEQ + jt * 64 + rowj) * ldin + h * HD + cold]);
    *reinterpret_cast<bf16x8*>(&tile[rowj][cold]) = v;
  }
  __syncthreads();
#pragma unroll
  for (int p = 0; p < 2; p++) {
    int rowd = p * 32 + (t >> 3);
    int colj = (t & 7) << 3;
    bf16x8 v;
#pragma unroll
    for (int jj = 0; jj < 8; jj++) v[jj] = tile[colj + jj][rowd];
    *reinterpret_cast<bf16x8*>(&out[((size_t)bh * HD + rowd) * SEQ + jt * 64 + colj]) = v;
  }
}

// ---------------- flash attention (causal), S^T form, merged dual-strip ----------------
// 1-D grid of 1024 blocks, XCD-affine decode: bh=(id>>7)*8+(id&7), bxi=(id>>3)&15
// -> all 16 blocks of a bh on ONE XCD; its L2 holds 8 bhs' K/V (FETCH 255->25MB,
// round 3). This round: the two passes (itile=bxi, then 31-bxi) are MERGED into
// ONE j-sweep: both q-strips consume the SAME staged K/V tile. Strip A (itile=
// bxi) active for jt<=bxi; strip B (itile=31-bxi) active for all jt<32-bxi.
// Effect: tile-iterations/barriers/staging 33 -> 32-bxi (avg 24.5, -26%), and
// on jt<=bxi each wave runs TWO independent slab chains (separate z/exp2/oacc)
// -> doubled ILP across the QK->softmax->PV dependency. Compute tiles remain
// exactly 33/block (uniform). j-tile 64, dbuf K/V (32KB LDS, 4 blocks/CU), one
// barrier per tile, prefetch before compute. Swizzles: 16B-chunk XOR (row&7),
// both-sides involution -> 2-way max on reads (free).
__global__ __launch_bounds__(256, 4) void attn(
    const bf16* __restrict__ Qn, const bf16* __restrict__ Kn, const bf16* __restrict__ Vt,
    bf16* __restrict__ O)
{
  __shared__ __align__(16) bf16 Ks[2][64 * 64];   // [j][d]
  __shared__ __align__(16) bf16 Vs[2][64 * 64];   // [d][j]

  const int id = blockIdx.x;
  const int bh = ((id >> 7) << 3) | (id & 7);     // same-bh blocks share an XCD
  const int bxi = (id >> 3) & 15;
  const int t = threadIdx.x, wave = t >> 6, lane = t & 63;
  const int q = lane >> 4, ln = lane & 15;
  const int b = bh >> 4, h = bh & 15;

  const int iA = bxi;                // lower strip, tiles 0..iA
  const int iB = 31 - bxi;           // upper strip, tiles 0..iB
  const int qbaseA = iA * 64 + wave * 16;
  const int qbaseB = iB * 64 + wave * 16;

  // staging: 2 chunks of 16B per tensor per thread (u0, u0+2048 elems)
  const int u0 = t * 8, u1 = t * 8 + 2048;
  const int kr0 = u0 >> 6, kc0 = ((u0 >> 3) & 7) ^ (kr0 & 7);
  const int kr1 = u1 >> 6, kc1 = ((u1 >> 3) & 7) ^ (kr1 & 7);
  const int vd0 = u0 >> 6, vc0 = ((u0 >> 3) & 7) ^ (vd0 & 7);
  const int vd1 = u1 >> 6, vc1 = ((u1 >> 3) & 7) ^ (vd1 & 7);
  const bf16* Kb = Kn + (size_t)bh * SEQ * HD;
  const bf16* Vb = Vt + (size_t)bh * HD * SEQ;

  f32x4 zero4 = {0.f, 0.f, 0.f, 0.f};

  // Q fragments for both strips (B-operand of S^T mfma)
  const bf16* qpA = Qn + ((size_t)bh * SEQ + qbaseA + ln) * HD + q * 8;
  const bf16* qpB = Qn + ((size_t)bh * SEQ + qbaseB + ln) * HD + q * 8;
  bf16x8 qfA0 = *reinterpret_cast<const bf16x8*>(qpA);
  bf16x8 qfA1 = *reinterpret_cast<const bf16x8*>(qpA + 32);
  bf16x8 qfB0 = *reinterpret_cast<const bf16x8*>(qpB);
  bf16x8 qfB1 = *reinterpret_cast<const bf16x8*>(qpB + 32);

  float lrowA = 0.f, lrowB = 0.f;
  f32x4 oaccA[4], oaccB[4];               // [md] tiles of O^T[d][i]
#pragma unroll
  for (int md = 0; md < 4; md++) { oaccA[md] = zero4; oaccB[md] = zero4; }

  // one 16x16 S^T slab vs one q-strip; accumulates into (oacc, lrow)
  auto slab = [&](int jslab, int jb, int buf, int qbase,
                  const bf16x8& qf0, const bf16x8& qf1,
                  f32x4* oacc, float& lrow) {
    if (jslab <= qbase + 15) {            // slab has unmasked elems for this wave
      const int rowj = jb * 16 + ln;
      bf16x8 kf0 = *reinterpret_cast<const bf16x8*>(
          &Ks[buf][rowj * 64 + ((q)     ^ (rowj & 7)) * 8]);
      bf16x8 kf1 = *reinterpret_cast<const bf16x8*>(
          &Ks[buf][rowj * 64 + ((4 + q) ^ (rowj & 7)) * 8]);
      f32x4 z = zero4;
      z = __builtin_amdgcn_mfma_f32_16x16x32_bf16(kf0, qf0, z, 0, 0, 0);
      z = __builtin_amdgcn_mfma_f32_16x16x32_bf16(kf1, qf1, z, 0, 0, 0);
      // z[r] = S^T[j = jslab+q*4+r][i = qbase+ln]
      if (jslab + 15 > qbase) {           // partial slab: mask
#pragma unroll
        for (int r = 0; r < 4; r++) {
          int jj = jslab + q * 4 + r;
          int ii = qbase + ln;
          if (jj > ii) z[r] = -1.0e30f;
        }
      }
      // fixed-max softmax (|s*log2e| <= 2.9 after per-head LN): p = 2^s
      float p0 = exp2f(z[0]), p1 = exp2f(z[1]), p2 = exp2f(z[2]), p3 = exp2f(z[3]);
      lrow += (p0 + p1) + (p2 + p3);
      bf16x4 pk = { (bf16)p0, (bf16)p1, (bf16)p2, (bf16)p3 };   // B-frag (k=j, n=i)

      // O^T += V^T * P^T for this 16-j slab
#pragma unroll
      for (int md = 0; md < 4; md++) {
        const int rowd = md * 16 + ln;
        const bf16* vp = &Vs[buf][rowd * 64 +
            (((jb * 2 + (q >> 1)) ^ (rowd & 7)) * 8) + (q & 1) * 4];
        bf16x4 vf = *reinterpret_cast<const bf16x4*>(vp);
        oacc[md] = mfma_pv(vf, pk, oacc[md]);
      }
    }
  };

  const int nj = iB + 1;                  // 64-j tiles covering strip B (superset of A)

  {                                        // prologue: stage jt=0 into buf 0
    gld_lds16(Kb + (size_t)kr0 * HD + kc0 * 8, &Ks[0][u0]);
    gld_lds16(Kb + (size_t)kr1 * HD + kc1 * 8, &Ks[0][u1]);
    gld_lds16(Vb + (size_t)vd0 * SEQ + vc0 * 8, &Vs[0][u0]);
    gld_lds16(Vb + (size_t)vd1 * SEQ + vc1 * 8, &Vs[0][u1]);
  }

  for (int jt = 0; jt < nj; ++jt) {
    const int buf = jt & 1;
    const int j0 = jt * 64;
    __syncthreads();                      // buf staged & visible; buf^1 reads drained
    if (jt + 1 < nj) {                    // prefetch next tile into other buffer
      const int jn = j0 + 64;
      gld_lds16(Kb + (size_t)(jn + kr0) * HD + kc0 * 8, &Ks[buf ^ 1][u0]);
      gld_lds16(Kb + (size_t)(jn + kr1) * HD + kc1 * 8, &Ks[buf ^ 1][u1]);
      gld_lds16(Vb + (size_t)vd0 * SEQ + jn + vc0 * 8, &Vs[buf ^ 1][u0]);
      gld_lds16(Vb + (size_t)vd1 * SEQ + jn + vc1 * 8, &Vs[buf ^ 1][u1]);
    }

    if (jt <= iA) {                       // strip A active
#pragma unroll
      for (int jb = 0; jb < 4; ++jb)
        slab(j0 + jb * 16, jb, buf, qbaseA, qfA0, qfA1, oaccA, lrowA);
    }
    {                                     // strip B always active (jt <= iB)
#pragma unroll
      for (int jb = 0; jb < 4; ++jb)
        slab(j0 + jb * 16, jb, buf, qbaseB, qfB0, qfB1, oaccB, lrowB);
    }
  }

  // epilogue: reduce l over the 4 quads holding each column i, normalize, store
#pragma unroll
  for (int sidx = 0; sidx < 2; ++sidx) {
    float s = sidx ? lrowB : lrowA;
    f32x4* oacc = sidx ? oaccB : oaccA;
    const int qb = sidx ? qbaseB : qbaseA;
    s += __shfl_xor(s, 16, 64);
    s += __shfl_xor(s, 32, 64);
    const float inv = 1.f / s;
    const int row = qb + ln;
#pragma unroll
    for (int md = 0; md < 4; md++) {
      bf16x4 o4 = { (bf16)(oacc[md][0] * inv), (bf16)(oacc[md][1] * inv),
                    (bf16)(oacc[md][2] * inv), (bf16)(oacc[md][3] * inv) };
      int col = h * HD + md * 16 + q * 4;  // 4 consecutive d
      *reinterpret_cast<bf16x4*>(&O[(size_t)(b * SEQ + row) * EMB + col]) = o4;
    }
  }
}

// ---------------- launch ----------------
extern "C" void kernel_launch(void* const* d_in, const int* in_sizes, int n_in,
                              void* d_out, int out_size, void* d_ws, size_t ws_size,
                              hipStream_t stream)
{
  const float* x   = (const float*)d_in[0];
  const float* Wk  = (const float*)d_in[1];
  const float* Wq  = (const float*)d_in[2];
  const float* Wv  = (const float*)d_in[3];
  const float* Wo  = (const float*)d_in[4];
  const float* bo  = (const float*)d_in[5];
  const float* klg = (const float*)d_in[6];
  const float* klb = (const float*)d_in[7];
  const float* qlg = (const float*)d_in[8];
  const float* qlb = (const float*)d_in[9];
  float* out = (float*)d_out;

  char* ws = (char*)d_ws;
  const size_t OFF_XB  = 0;
  const size_t OFF_WB  = OFF_XB  + (size_t)BT * EMB * 2;
  const size_t OFF_KQV = OFF_WB  + (size_t)4 * EMB * EMB * 2;
  const size_t OFF_KN  = OFF_KQV + (size_t)BT * 3 * EMB * 2;
  const size_t OFF_QN  = OFF_KN  + (size_t)BT * EMB * 2;
  const size_t OFF_VT  = OFF_QN  + (size_t)BT * EMB * 2;
  const size_t OFF_END = OFF_VT  + (size_t)BT * EMB * 2;
  if (ws_size < OFF_END) return;

  bf16* xb   = (bf16*)(ws + OFF_XB);
  bf16* wb   = (bf16*)(ws + OFF_WB);
  bf16* kqv  = (bf16*)(ws + OFF_KQV);
  bf16* kn   = (bf16*)(ws + OFF_KN);
  bf16* qn   = (bf16*)(ws + OFF_QN);
  bf16* vt   = (bf16*)(ws + OFF_VT);
  bf16* ob   = (bf16*)(ws + OFF_KQV);    // alias: KQV dead after ln/v_trans

  cvt_f32_bf16<<<(BT * EMB / 4) / 256, 256, 0, stream>>>(x, xb, BT * EMB / 4);
  cvt_w4<<<(4 * EMB * EMB / 4) / 256, 256, 0, stream>>>(Wk, Wq, Wv, Wo, wb);

  gemm_bt<0><<<dim3(3 * EMB / 128, BT / 128), 256, 0, stream>>>(
      xb, wb, kqv, (float*)nullptr, (const float*)nullptr, BT, 3 * EMB, EMB);

  ln_kq<<<BT * HEADS / 32, 256, 0, stream>>>(kqv, kn, qn, klg, klb, qlg, qlb,
                                             QK_SCALE * LOG2E, QK_SCALE);
  v_trans<<<dim3(SEQ / 64, BATCH * HEADS), 256, 0, stream>>>(kqv + 2 * EMB, 3 * EMB, vt);

  attn<<<dim3(16 * BATCH * HEADS), 256, 0, stream>>>(qn, kn, vt, ob);

  gemm_bt<1><<<dim3(EMB / 128, BT / 128), 256, 0, stream>>>(
      ob, wb + (size_t)3 * EMB * EMB, (bf16*)nullptr, out, bo, BT, EMB, EMB);
}

// Round 6
// 279.841 us; speedup vs baseline: 1.0864x; 1.0325x over previous
//
#include <hip/hip_runtime.h>
#include <hip/hip_bf16.h>
#include <cstdint>

#define EMB 1024
#define HEADS 16
#define HD 64
#define BATCH 4
#define SEQ 2048
#define BT (BATCH*SEQ)                 // 8192 tokens
#define LNEPS 1e-5f
#define QK_SCALE 0.17677669529663687f  // 1024^-0.25
#define LOG2E 1.4426950408889634f

typedef __bf16 bf16;
typedef __bf16 bf16x8 __attribute__((ext_vector_type(8)));
typedef __bf16 bf16x4 __attribute__((ext_vector_type(4)));
typedef float  f32x4  __attribute__((ext_vector_type(4)));
typedef short  s16x4  __attribute__((ext_vector_type(4)));

typedef const __attribute__((address_space(1))) void* gas_ptr;
typedef __attribute__((address_space(3))) void*       las_ptr;

__device__ __forceinline__ void gld_lds16(const void* g, void* l) {
  __builtin_amdgcn_global_load_lds((gas_ptr)g, (las_ptr)l, 16, 0, 0);
}

// PV matmul: 16x16x16 bf16 MFMA (C-layout of S^T == B-layout of this shape).
__device__ __forceinline__ f32x4 mfma_pv(bf16x4 a, bf16x4 b, f32x4 c) {
  return __builtin_amdgcn_mfma_f32_16x16x16bf16_1k(
      __builtin_bit_cast(s16x4, a), __builtin_bit_cast(s16x4, b), c, 0, 0, 0);
}

// ---------------- fused fp32->bf16 conversions (x + 4 weight mats) ----------------
// blocks [0,8192): x (2M float4); blocks [8192,12288): W4 (1M float4).
__global__ void cvt_all(const float* __restrict__ x,
                        const float* __restrict__ w0, const float* __restrict__ w1,
                        const float* __restrict__ w2, const float* __restrict__ w3,
                        bf16* __restrict__ xb, bf16* __restrict__ wb) {
  const int bid = blockIdx.x;
  if (bid < 8192) {
    int i = bid * 256 + threadIdx.x;           // over BT*EMB/4 float4s
    float4 f = reinterpret_cast<const float4*>(x)[i];
    bf16x4 o = { (bf16)f.x, (bf16)f.y, (bf16)f.z, (bf16)f.w };
    reinterpret_cast<bf16x4*>(xb)[i] = o;
  } else {
    int i = (bid - 8192) * 256 + threadIdx.x;  // over 4*EMB*EMB/4 float4s
    int sel = i >> 18;
    int j = i & 262143;
    const float* s = (sel == 0) ? w0 : (sel == 1) ? w1 : (sel == 2) ? w2 : w3;
    float4 f = reinterpret_cast<const float4*>(s)[j];
    bf16x4 o = { (bf16)f.x, (bf16)f.y, (bf16)f.z, (bf16)f.w };
    reinterpret_cast<bf16x4*>(wb)[i] = o;
  }
}

// ---------------- m97-style GEMM: C[M][N] = A[M][K] * B[N][K]^T ----------------
// XCD-affine block remap (requires gridDim.y == 64): lid=(by*gx+bx) dispatches
// round-robin lid%8 -> XCD. Remap so each XCD owns 8 contiguous M-rows x ALL
// N-cols, x-outer / y-inner: resident panel set per XCD = 2MB A + 2MB B = 4MB
// = its L2 (default mapping scatters ~32MB -> thrash). Bijective:
// xcd=lid&7, n=lid>>3, bx=n>>3, by=xcd*8+(n&7).
template<int OUTF32>
__global__ __launch_bounds__(256, 2) void gemm_bt(
    const bf16* __restrict__ A, const bf16* __restrict__ Bm,
    bf16* __restrict__ Cb, float* __restrict__ Cf, const float* __restrict__ bias,
    int M, int N, int K)
{
  __shared__ __align__(16) bf16 As[128 * 32];
  __shared__ __align__(16) bf16 Bs[128 * 32];

  const int t    = threadIdx.x;
  const int lane = t & 63;
  const int wave = t >> 6;
  const int q    = lane >> 4;
  const int ln   = lane & 15;

  const int lid = (int)blockIdx.y * (int)gridDim.x + (int)blockIdx.x;
  const int xcd = lid & 7;
  const int nn  = lid >> 3;
  const int bxr = nn >> 3;                 // [0, gridDim.x)
  const int byr = (xcd << 3) | (nn & 7);   // [0, 64)
  const int m0  = byr * 128;
  const int n0  = bxr * 128;

  const int wm   = (wave >> 1) * 64;
  const int wn   = (wave & 1) * 64;

  const int r0 = t >> 2;
  const int c0 = (t & 3) << 3;

  f32x4 zero4 = {0.f, 0.f, 0.f, 0.f};
  f32x4 acc[4][4];
#pragma unroll
  for (int i = 0; i < 4; i++)
#pragma unroll
    for (int j = 0; j < 4; j++) acc[i][j] = zero4;

  for (int k0 = 0; k0 < K; k0 += 32) {
    __syncthreads();
    const bf16* ga = A  + (size_t)(m0 + r0) * K + k0 + c0;
    const bf16* gb = Bm + (size_t)(n0 + r0) * K + k0 + c0;
    gld_lds16(ga,                  &As[t * 8]);
    gld_lds16(ga + (size_t)64 * K, &As[t * 8 + 2048]);
    gld_lds16(gb,                  &Bs[t * 8]);
    gld_lds16(gb + (size_t)64 * K, &Bs[t * 8 + 2048]);
    __syncthreads();

    bf16x8 af[4], bfr[4];
#pragma unroll
    for (int mi = 0; mi < 4; mi++)
      af[mi] = *reinterpret_cast<const bf16x8*>(&As[(wm + mi * 16 + ln) * 32 + q * 8]);
#pragma unroll
    for (int ni = 0; ni < 4; ni++)
      bfr[ni] = *reinterpret_cast<const bf16x8*>(&Bs[(wn + ni * 16 + ln) * 32 + q * 8]);
#pragma unroll
    for (int mi = 0; mi < 4; mi++)
#pragma unroll
      for (int ni = 0; ni < 4; ni++)
        acc[mi][ni] = __builtin_amdgcn_mfma_f32_16x16x32_bf16(af[mi], bfr[ni], acc[mi][ni], 0, 0, 0);
  }

#pragma unroll
  for (int mi = 0; mi < 4; mi++) {
#pragma unroll
    for (int ni = 0; ni < 4; ni++) {
#pragma unroll
      for (int r = 0; r < 4; r++) {
        int row = m0 + wm + mi * 16 + q * 4 + r;
        int col = n0 + wn + ni * 16 + ln;
        float v = acc[mi][ni][r];
        if (OUTF32) Cf[(size_t)row * N + col] = v + bias[col];
        else        Cb[(size_t)row * N + col] = (bf16)v;
      }
    }
  }
}

// ---------------- fused: per-head LayerNorm (K,Q) + V transpose ----------------
// blocks [0,4096): LN. kqv: [8192][3072]; K at col 0, Q at col 1024 -> kn,qn
//   [bh][t][64]. 8 lanes/row, bf16x8 io. kscale includes log2(e).
// blocks [4096,6144): V transpose. kqv col 2048 [t][3072] -> vt [bh][64 d][2048 t].
__global__ void ln_vt(const bf16* __restrict__ kqv,
                      bf16* __restrict__ kn, bf16* __restrict__ qn,
                      bf16* __restrict__ vt,
                      const float* __restrict__ kg, const float* __restrict__ kb,
                      const float* __restrict__ qg, const float* __restrict__ qb,
                      float kscale, float qscale)
{
  __shared__ __align__(16) bf16 tile[64][72];
  const int bid = blockIdx.x;
  const int t = threadIdx.x;
  if (bid < 4096) {
    const int lr = t & 7;                       // lane within row
    const int row = bid * 32 + (t >> 3);        // row = tok*16 + h
    const int tok = row >> 4, h = row & 15;
    const size_t base = (size_t)tok * (3 * EMB) + h * HD + lr * 8;

    bf16x8 vk = *reinterpret_cast<const bf16x8*>(kqv + base);
    bf16x8 vq = *reinterpret_cast<const bf16x8*>(kqv + base + EMB);

    float fk[8], fq[8];
    float sk = 0.f, sq = 0.f, s2k = 0.f, s2q = 0.f;
#pragma unroll
    for (int e = 0; e < 8; e++) {
      fk[e] = (float)vk[e]; fq[e] = (float)vq[e];
      sk += fk[e]; sq += fq[e];
      s2k += fk[e] * fk[e]; s2q += fq[e] * fq[e];
    }
#pragma unroll
    for (int m = 1; m < 8; m <<= 1) {
      sk  += __shfl_xor(sk,  m, 64); sq  += __shfl_xor(sq,  m, 64);
      s2k += __shfl_xor(s2k, m, 64); s2q += __shfl_xor(s2q, m, 64);
    }
    float mk = sk * (1.f / 64.f), mq = sq * (1.f / 64.f);
    float rk = rsqrtf(s2k * (1.f / 64.f) - mk * mk + LNEPS) * kscale;
    float rq = rsqrtf(s2q * (1.f / 64.f) - mq * mq + LNEPS) * qscale;

    bf16x8 ok, oq;
#pragma unroll
    for (int e = 0; e < 8; e++) {
      float gk = kg[lr * 8 + e], bk2 = kb[lr * 8 + e];
      float gq = qg[lr * 8 + e], bq2 = qb[lr * 8 + e];
      ok[e] = (bf16)(((fk[e] - mk) * rk) * gk + bk2 * kscale);
      oq[e] = (bf16)(((fq[e] - mq) * rq) * gq + bq2 * qscale);
    }
    const int b = tok >> 11, tt = tok & 2047;
    const size_t o = ((size_t)(b * HEADS + h) * SEQ + tt) * HD + lr * 8;
    *reinterpret_cast<bf16x8*>(kn + o) = ok;
    *reinterpret_cast<bf16x8*>(qn + o) = oq;
  } else {
    const int idx = bid - 4096;
    const int jt = idx & 31, bh = idx >> 5;
    const int b = bh >> 4, h = bh & 15;
    const bf16* in = kqv + 2 * EMB;
#pragma unroll
    for (int p = 0; p < 2; p++) {
      int rowj = p * 32 + (t >> 3);
      int cold = (t & 7) << 3;
      bf16x8 v = *reinterpret_cast<const bf16x8*>(
          &in[(size_t)(b * SEQ + jt * 64 + rowj) * (3 * EMB) + h * HD + cold]);
      *reinterpret_cast<bf16x8*>(&tile[rowj][cold]) = v;
    }
    __syncthreads();
#pragma unroll
    for (int p = 0; p < 2; p++) {
      int rowd = p * 32 + (t >> 3);
      int colj = (t & 7) << 3;
      bf16x8 v;
#pragma unroll
      for (int jj = 0; jj < 8; jj++) v[jj] = tile[colj + jj][rowd];
      *reinterpret_cast<bf16x8*>(&vt[((size_t)bh * HD + rowd) * SEQ + jt * 64 + colj]) = v;
    }
  }
}

// ---------------- flash attention (causal), S^T form, paired tiles + dbuf ----------------
// 1-D grid of 1024 blocks, XCD-affine decode: xcd=id&7, bx=(id>>3)&15,
// bh=(id>>7)*8+xcd -> all 16 blocks of a bh on ONE XCD (its L2 holds 8 bhs'
// K/V; FETCH 255->25MB, round 3). Pass pairing (bx then 31-bx): uniform 33
// j-steps per block. j-tile 64, double-buffered K/V (32KB LDS, 4 blocks/CU),
// one barrier per tile, prefetch issued before compute. Swizzles: 16B-chunk
// XOR (row&7), both-sides involution -> 2-way max on reads (free).
__global__ __launch_bounds__(256, 4) void attn(
    const bf16* __restrict__ Qn, const bf16* __restrict__ Kn, const bf16* __restrict__ Vt,
    bf16* __restrict__ O)
{
  __shared__ __align__(16) bf16 Ks[2][64 * 64];   // [j][d]
  __shared__ __align__(16) bf16 Vs[2][64 * 64];   // [d][j]

  const int id = blockIdx.x;
  const int bh = ((id >> 7) << 3) | (id & 7);     // same-bh blocks share an XCD
  const int bxi = (id >> 3) & 15;
  const int t = threadIdx.x, wave = t >> 6, lane = t & 63;
  const int q = lane >> 4, ln = lane & 15;
  const int b = bh >> 4, h = bh & 15;

  // staging: 2 chunks of 16B per tensor per thread (u0, u0+2048 elems)
  const int u0 = t * 8, u1 = t * 8 + 2048;
  const int kr0 = u0 >> 6, kc0 = ((u0 >> 3) & 7) ^ (kr0 & 7);
  const int kr1 = u1 >> 6, kc1 = ((u1 >> 3) & 7) ^ (kr1 & 7);
  const int vd0 = u0 >> 6, vc0 = ((u0 >> 3) & 7) ^ (vd0 & 7);
  const int vd1 = u1 >> 6, vc1 = ((u1 >> 3) & 7) ^ (vd1 & 7);
  const bf16* Kb = Kn + (size_t)bh * SEQ * HD;
  const bf16* Vb = Vt + (size_t)bh * HD * SEQ;

  f32x4 zero4 = {0.f, 0.f, 0.f, 0.f};

  for (int pass = 0; pass < 2; ++pass) {
    const int itile = pass ? (31 - bxi) : bxi;
    const int qbase = itile * 64 + wave * 16;

    // Q fragments (B-operand of S^T mfma): Q[i=qbase+ln][d=ks*32+q*8 ..+8]
    const bf16* qp = Qn + ((size_t)bh * SEQ + qbase + ln) * HD + q * 8;
    bf16x8 qf0 = *reinterpret_cast<const bf16x8*>(qp);
    bf16x8 qf1 = *reinterpret_cast<const bf16x8*>(qp + 32);

    float lrow = 0.f;
    f32x4 oacc[4];                          // [md] tiles of O^T[d][i]
#pragma unroll
    for (int md = 0; md < 4; md++) oacc[md] = zero4;

    const int nj = itile + 1;               // 64-j tiles covering 0..i0+63

    __syncthreads();                        // prior pass/iter reads done before overwrite
    {                                       // prologue: stage jt=0 into buf 0
      gld_lds16(Kb + (size_t)kr0 * HD + kc0 * 8, &Ks[0][u0]);
      gld_lds16(Kb + (size_t)kr1 * HD + kc1 * 8, &Ks[0][u1]);
      gld_lds16(Vb + (size_t)vd0 * SEQ + vc0 * 8, &Vs[0][u0]);
      gld_lds16(Vb + (size_t)vd1 * SEQ + vc1 * 8, &Vs[0][u1]);
    }

    for (int jt = 0; jt < nj; ++jt) {
      const int buf = jt & 1;
      const int j0 = jt * 64;
      __syncthreads();                      // buf staged & visible; buf^1 reads drained
      if (jt + 1 < nj) {                    // prefetch next tile into other buffer
        const int jn = j0 + 64;
        gld_lds16(Kb + (size_t)(jn + kr0) * HD + kc0 * 8, &Ks[buf ^ 1][u0]);
        gld_lds16(Kb + (size_t)(jn + kr1) * HD + kc1 * 8, &Ks[buf ^ 1][u1]);
        gld_lds16(Vb + (size_t)vd0 * SEQ + jn + vc0 * 8, &Vs[buf ^ 1][u0]);
        gld_lds16(Vb + (size_t)vd1 * SEQ + jn + vc1 * 8, &Vs[buf ^ 1][u1]);
      }

#pragma unroll
      for (int jb = 0; jb < 4; ++jb) {
        const int jslab = j0 + jb * 16;
        if (jslab <= qbase + 15) {          // slab has unmasked elems for this wave
          const int rowj = jb * 16 + ln;
          bf16x8 kf0 = *reinterpret_cast<const bf16x8*>(
              &Ks[buf][rowj * 64 + ((q)     ^ (rowj & 7)) * 8]);
          bf16x8 kf1 = *reinterpret_cast<const bf16x8*>(
              &Ks[buf][rowj * 64 + ((4 + q) ^ (rowj & 7)) * 8]);
          f32x4 z = zero4;
          z = __builtin_amdgcn_mfma_f32_16x16x32_bf16(kf0, qf0, z, 0, 0, 0);
          z = __builtin_amdgcn_mfma_f32_16x16x32_bf16(kf1, qf1, z, 0, 0, 0);
          // z[r] = S^T[j = jslab+q*4+r][i = qbase+ln]
          if (jslab + 15 > qbase) {         // partial slab: mask
#pragma unroll
            for (int r = 0; r < 4; r++) {
              int jj = jslab + q * 4 + r;
              int ii = qbase + ln;
              if (jj > ii) z[r] = -1.0e30f;
            }
          }
          // fixed-max softmax (|s*log2e| <= 2.9 after per-head LN): p = 2^s
          float p0 = exp2f(z[0]), p1 = exp2f(z[1]), p2 = exp2f(z[2]), p3 = exp2f(z[3]);
          lrow += (p0 + p1) + (p2 + p3);
          bf16x4 pk = { (bf16)p0, (bf16)p1, (bf16)p2, (bf16)p3 };   // B-frag (k=j, n=i)

          // O^T += V^T * P^T for this 16-j slab
#pragma unroll
          for (int md = 0; md < 4; md++) {
            const int rowd = md * 16 + ln;
            const bf16* vp = &Vs[buf][rowd * 64 +
                (((jb * 2 + (q >> 1)) ^ (rowd & 7)) * 8) + (q & 1) * 4];
            bf16x4 vf = *reinterpret_cast<const bf16x4*>(vp);
            oacc[md] = mfma_pv(vf, pk, oacc[md]);
          }
        }
      }
    }

    // epilogue: reduce l over the 4 quads holding each column i, normalize, store
    float s = lrow;
    s += __shfl_xor(s, 16, 64);
    s += __shfl_xor(s, 32, 64);
    const float inv = 1.f / s;
    const int row = qbase + ln;
#pragma unroll
    for (int md = 0; md < 4; md++) {
      bf16x4 o4 = { (bf16)(oacc[md][0] * inv), (bf16)(oacc[md][1] * inv),
                    (bf16)(oacc[md][2] * inv), (bf16)(oacc[md][3] * inv) };
      int col = h * HD + md * 16 + q * 4;    // 4 consecutive d
      *reinterpret_cast<bf16x4*>(&O[(size_t)(b * SEQ + row) * EMB + col]) = o4;
    }
  }
}

// ---------------- launch ----------------
extern "C" void kernel_launch(void* const* d_in, const int* in_sizes, int n_in,
                              void* d_out, int out_size, void* d_ws, size_t ws_size,
                              hipStream_t stream)
{
  const float* x   = (const float*)d_in[0];
  const float* Wk  = (const float*)d_in[1];
  const float* Wq  = (const float*)d_in[2];
  const float* Wv  = (const float*)d_in[3];
  const float* Wo  = (const float*)d_in[4];
  const float* bo  = (const float*)d_in[5];
  const float* klg = (const float*)d_in[6];
  const float* klb = (const float*)d_in[7];
  const float* qlg = (const float*)d_in[8];
  const float* qlb = (const float*)d_in[9];
  float* out = (float*)d_out;

  char* ws = (char*)d_ws;
  const size_t OFF_XB  = 0;
  const size_t OFF_WB  = OFF_XB  + (size_t)BT * EMB * 2;
  const size_t OFF_KQV = OFF_WB  + (size_t)4 * EMB * EMB * 2;
  const size_t OFF_KN  = OFF_KQV + (size_t)BT * 3 * EMB * 2;
  const size_t OFF_QN  = OFF_KN  + (size_t)BT * EMB * 2;
  const size_t OFF_VT  = OFF_QN  + (size_t)BT * EMB * 2;
  const size_t OFF_END = OFF_VT  + (size_t)BT * EMB * 2;
  if (ws_size < OFF_END) return;

  bf16* xb   = (bf16*)(ws + OFF_XB);
  bf16* wb   = (bf16*)(ws + OFF_WB);
  bf16* kqv  = (bf16*)(ws + OFF_KQV);
  bf16* kn   = (bf16*)(ws + OFF_KN);
  bf16* qn   = (bf16*)(ws + OFF_QN);
  bf16* vt   = (bf16*)(ws + OFF_VT);
  bf16* ob   = (bf16*)(ws + OFF_KQV);    // alias: KQV dead after ln_vt

  cvt_all<<<12288, 256, 0, stream>>>(x, Wk, Wq, Wv, Wo, xb, wb);

  gemm_bt<0><<<dim3(3 * EMB / 128, BT / 128), 256, 0, stream>>>(
      xb, wb, kqv, (float*)nullptr, (const float*)nullptr, BT, 3 * EMB, EMB);

  ln_vt<<<4096 + 2048, 256, 0, stream>>>(kqv, kn, qn, vt, klg, klb, qlg, qlb,
                                         QK_SCALE * LOG2E, QK_SCALE);

  attn<<<dim3(16 * BATCH * HEADS), 256, 0, stream>>>(qn, kn, vt, ob);

  gemm_bt<1><<<dim3(EMB / 128, BT / 128), 256, 0, stream>>>(
      ob, wb + (size_t)3 * EMB * EMB, (bf16*)nullptr, out, bo, BT, EMB, EMB);
}

// Round 7
// 267.203 us; speedup vs baseline: 1.1378x; 1.0473x over previous
//
#include <hip/hip_runtime.h>
#include <hip/hip_bf16.h>
#include <cstdint>

#define EMB 1024
#define HEADS 16
#define HD 64
#define BATCH 4
#define SEQ 2048
#define BT (BATCH*SEQ)                 // 8192 tokens
#define LNEPS 1e-5f
#define QK_SCALE 0.17677669529663687f  // 1024^-0.25
#define LOG2E 1.4426950408889634f

typedef __bf16 bf16;
typedef __bf16 bf16x8 __attribute__((ext_vector_type(8)));
typedef __bf16 bf16x4 __attribute__((ext_vector_type(4)));
typedef float  f32x4  __attribute__((ext_vector_type(4)));
typedef short  s16x4  __attribute__((ext_vector_type(4)));

typedef const __attribute__((address_space(1))) void* gas_ptr;
typedef __attribute__((address_space(3))) void*       las_ptr;

__device__ __forceinline__ void gld_lds16(const void* g, void* l) {
  __builtin_amdgcn_global_load_lds((gas_ptr)g, (las_ptr)l, 16, 0, 0);
}

// PV matmul: 16x16x16 bf16 MFMA (C-layout of S^T == B-layout of this shape).
__device__ __forceinline__ f32x4 mfma_pv(bf16x4 a, bf16x4 b, f32x4 c) {
  return __builtin_amdgcn_mfma_f32_16x16x16bf16_1k(
      __builtin_bit_cast(s16x4, a), __builtin_bit_cast(s16x4, b), c, 0, 0, 0);
}

// ---------------- fused fp32->bf16 conversions (x + 4 weight mats) ----------------
// blocks [0,8192): x (2M float4); blocks [8192,12288): W4 (1M float4).
__global__ void cvt_all(const float* __restrict__ x,
                        const float* __restrict__ w0, const float* __restrict__ w1,
                        const float* __restrict__ w2, const float* __restrict__ w3,
                        bf16* __restrict__ xb, bf16* __restrict__ wb) {
  const int bid = blockIdx.x;
  if (bid < 8192) {
    int i = bid * 256 + threadIdx.x;           // over BT*EMB/4 float4s
    float4 f = reinterpret_cast<const float4*>(x)[i];
    bf16x4 o = { (bf16)f.x, (bf16)f.y, (bf16)f.z, (bf16)f.w };
    reinterpret_cast<bf16x4*>(xb)[i] = o;
  } else {
    int i = (bid - 8192) * 256 + threadIdx.x;  // over 4*EMB*EMB/4 float4s
    int sel = i >> 18;
    int j = i & 262143;
    const float* s = (sel == 0) ? w0 : (sel == 1) ? w1 : (sel == 2) ? w2 : w3;
    float4 f = reinterpret_cast<const float4*>(s)[j];
    bf16x4 o = { (bf16)f.x, (bf16)f.y, (bf16)f.z, (bf16)f.w };
    reinterpret_cast<bf16x4*>(wb)[i] = o;
  }
}

// ---------------- fused QKV GEMM + per-head LN(K,Q) + V transpose ----------------
// C[8192][3072] = xb[8192][1024] * wb[3072][1024]^T, but C never hits memory:
//   cols [0,1024):   K-proj -> per-head LN (scale QK_SCALE*LOG2E) -> kn [bh][t][64]
//   cols [1024,2048) Q-proj -> per-head LN (scale QK_SCALE)       -> qn [bh][t][64]
//   cols [2048,3072) V-proj ->                                       vt [bh][64][2048]
// Wave quadrant = 64 cols = exactly one head segment (n0%128==0, wn in {0,64}).
// LN over cols for row (mi,q,r): 4 in-lane adds over ni + shfl_xor{1,2,4,8}
// within the 16-lane ln-group (C-frag: row=q*4+r, col=ln — verified layout).
// XCD-affine remap (grid 24x64): lid=(by*gx+bx); xcd=lid&7; nn=lid>>3;
// bxr=nn>>3; byr=xcd*8+(nn&7) -> per-XCD resident panels ~4MB = its L2.
__global__ __launch_bounds__(256, 2) void gemm_kqv(
    const bf16* __restrict__ A, const bf16* __restrict__ Bm,
    bf16* __restrict__ kn, bf16* __restrict__ qn, bf16* __restrict__ vt,
    const float* __restrict__ kg, const float* __restrict__ kb,
    const float* __restrict__ qg, const float* __restrict__ qb)
{
  __shared__ __align__(16) bf16 As[128 * 32];
  __shared__ __align__(16) bf16 Bs[128 * 32];

  const int K = EMB;
  const int t    = threadIdx.x;
  const int lane = t & 63;
  const int wave = t >> 6;
  const int q    = lane >> 4;
  const int ln   = lane & 15;

  const int lid = (int)blockIdx.y * (int)gridDim.x + (int)blockIdx.x;
  const int xcd = lid & 7;
  const int nn  = lid >> 3;
  const int bxr = nn >> 3;                 // [0, 24)
  const int byr = (xcd << 3) | (nn & 7);   // [0, 64)
  const int m0  = byr * 128;
  const int n0  = bxr * 128;

  const int wm = (wave >> 1) * 64;
  const int wn = (wave & 1) * 64;

  const int r0 = t >> 2;
  const int c0 = (t & 3) << 3;

  f32x4 zero4 = {0.f, 0.f, 0.f, 0.f};
  f32x4 acc[4][4];
#pragma unroll
  for (int i = 0; i < 4; i++)
#pragma unroll
    for (int j = 0; j < 4; j++) acc[i][j] = zero4;

  for (int k0 = 0; k0 < K; k0 += 32) {
    __syncthreads();
    const bf16* ga = A  + (size_t)(m0 + r0) * K + k0 + c0;
    const bf16* gb = Bm + (size_t)(n0 + r0) * K + k0 + c0;
    gld_lds16(ga,                  &As[t * 8]);
    gld_lds16(ga + (size_t)64 * K, &As[t * 8 + 2048]);
    gld_lds16(gb,                  &Bs[t * 8]);
    gld_lds16(gb + (size_t)64 * K, &Bs[t * 8 + 2048]);
    __syncthreads();

    bf16x8 af[4], bfr[4];
#pragma unroll
    for (int mi = 0; mi < 4; mi++)
      af[mi] = *reinterpret_cast<const bf16x8*>(&As[(wm + mi * 16 + ln) * 32 + q * 8]);
#pragma unroll
    for (int ni = 0; ni < 4; ni++)
      bfr[ni] = *reinterpret_cast<const bf16x8*>(&Bs[(wn + ni * 16 + ln) * 32 + q * 8]);
#pragma unroll
    for (int mi = 0; mi < 4; mi++)
#pragma unroll
      for (int ni = 0; ni < 4; ni++)
        acc[mi][ni] = __builtin_amdgcn_mfma_f32_16x16x32_bf16(af[mi], bfr[ni], acc[mi][ni], 0, 0, 0);
  }

  // ---- epilogue ----
  const int sec = n0 >> 10;                 // 0=K, 1=Q, 2=V
  const int cb  = (n0 & 1023) + wn;         // col within projection
  const int h   = cb >> 6;                  // head
  const int R0  = m0 + wm;

  if (sec == 2) {
    // V: write transposed [bh][d][t]; lane holds 4 consecutive t at fixed d
#pragma unroll
    for (int mi = 0; mi < 4; mi++) {
      const int R = R0 + mi * 16 + q * 4;
      const int b = R >> 11, tt = R & 2047;
#pragma unroll
      for (int ni = 0; ni < 4; ni++) {
        const int d = ni * 16 + ln;
        bf16x4 o4 = { (bf16)acc[mi][ni][0], (bf16)acc[mi][ni][1],
                      (bf16)acc[mi][ni][2], (bf16)acc[mi][ni][3] };
        *reinterpret_cast<bf16x4*>(
            &vt[((size_t)(b * HEADS + h) * HD + d) * SEQ + tt]) = o4;
      }
    }
  } else {
    const float scale = sec ? QK_SCALE : (QK_SCALE * LOG2E);
    const float* gp = sec ? qg : kg;
    const float* bp = sec ? qb : kb;
    bf16* outp = sec ? qn : kn;
    float gv[4], bv[4];
#pragma unroll
    for (int ni = 0; ni < 4; ni++) {
      gv[ni] = gp[ni * 16 + ln];
      bv[ni] = bp[ni * 16 + ln] * scale;
    }
#pragma unroll
    for (int mi = 0; mi < 4; mi++) {
#pragma unroll
      for (int r = 0; r < 4; r++) {
        const float x0 = acc[mi][0][r], x1 = acc[mi][1][r];
        const float x2 = acc[mi][2][r], x3 = acc[mi][3][r];
        float s  = (x0 + x1) + (x2 + x3);
        float s2 = (x0 * x0 + x1 * x1) + (x2 * x2 + x3 * x3);
#pragma unroll
        for (int mm = 1; mm < 16; mm <<= 1) {
          s  += __shfl_xor(s,  mm, 64);
          s2 += __shfl_xor(s2, mm, 64);
        }
        const float mean = s * (1.f / 64.f);
        const float rs = rsqrtf(s2 * (1.f / 64.f) - mean * mean + LNEPS) * scale;
        const int R = R0 + mi * 16 + q * 4 + r;
        const int b = R >> 11, tt = R & 2047;
        const size_t o = ((size_t)(b * HEADS + h) * SEQ + tt) * HD + ln;
#pragma unroll
        for (int ni = 0; ni < 4; ni++)
          outp[o + ni * 16] = (bf16)((acc[mi][ni][r] - mean) * rs * gv[ni] + bv[ni]);
      }
    }
  }
}

// ---------------- m97-style GEMM: C[M][N] = A[M][K] * B[N][K]^T (output proj) ----------------
// Same XCD-affine remap (requires gridDim.y == 64).
template<int OUTF32>
__global__ __launch_bounds__(256, 2) void gemm_bt(
    const bf16* __restrict__ A, const bf16* __restrict__ Bm,
    bf16* __restrict__ Cb, float* __restrict__ Cf, const float* __restrict__ bias,
    int M, int N, int K)
{
  __shared__ __align__(16) bf16 As[128 * 32];
  __shared__ __align__(16) bf16 Bs[128 * 32];

  const int t    = threadIdx.x;
  const int lane = t & 63;
  const int wave = t >> 6;
  const int q    = lane >> 4;
  const int ln   = lane & 15;

  const int lid = (int)blockIdx.y * (int)gridDim.x + (int)blockIdx.x;
  const int xcd = lid & 7;
  const int nn  = lid >> 3;
  const int bxr = nn >> 3;                 // [0, gridDim.x)
  const int byr = (xcd << 3) | (nn & 7);   // [0, 64)
  const int m0  = byr * 128;
  const int n0  = bxr * 128;

  const int wm   = (wave >> 1) * 64;
  const int wn   = (wave & 1) * 64;

  const int r0 = t >> 2;
  const int c0 = (t & 3) << 3;

  f32x4 zero4 = {0.f, 0.f, 0.f, 0.f};
  f32x4 acc[4][4];
#pragma unroll
  for (int i = 0; i < 4; i++)
#pragma unroll
    for (int j = 0; j < 4; j++) acc[i][j] = zero4;

  for (int k0 = 0; k0 < K; k0 += 32) {
    __syncthreads();
    const bf16* ga = A  + (size_t)(m0 + r0) * K + k0 + c0;
    const bf16* gb = Bm + (size_t)(n0 + r0) * K + k0 + c0;
    gld_lds16(ga,                  &As[t * 8]);
    gld_lds16(ga + (size_t)64 * K, &As[t * 8 + 2048]);
    gld_lds16(gb,                  &Bs[t * 8]);
    gld_lds16(gb + (size_t)64 * K, &Bs[t * 8 + 2048]);
    __syncthreads();

    bf16x8 af[4], bfr[4];
#pragma unroll
    for (int mi = 0; mi < 4; mi++)
      af[mi] = *reinterpret_cast<const bf16x8*>(&As[(wm + mi * 16 + ln) * 32 + q * 8]);
#pragma unroll
    for (int ni = 0; ni < 4; ni++)
      bfr[ni] = *reinterpret_cast<const bf16x8*>(&Bs[(wn + ni * 16 + ln) * 32 + q * 8]);
#pragma unroll
    for (int mi = 0; mi < 4; mi++)
#pragma unroll
      for (int ni = 0; ni < 4; ni++)
        acc[mi][ni] = __builtin_amdgcn_mfma_f32_16x16x32_bf16(af[mi], bfr[ni], acc[mi][ni], 0, 0, 0);
  }

#pragma unroll
  for (int mi = 0; mi < 4; mi++) {
#pragma unroll
    for (int ni = 0; ni < 4; ni++) {
#pragma unroll
      for (int r = 0; r < 4; r++) {
        int row = m0 + wm + mi * 16 + q * 4 + r;
        int col = n0 + wn + ni * 16 + ln;
        float v = acc[mi][ni][r];
        if (OUTF32) Cf[(size_t)row * N + col] = v + bias[col];
        else        Cb[(size_t)row * N + col] = (bf16)v;
      }
    }
  }
}

// ---------------- flash attention (causal), S^T form, paired tiles + dbuf ----------------
// 1-D grid of 1024 blocks, XCD-affine decode: xcd=id&7, bx=(id>>3)&15,
// bh=(id>>7)*8+xcd -> all 16 blocks of a bh on ONE XCD (its L2 holds 8 bhs'
// K/V; FETCH 255->25MB, round 3). Pass pairing (bx then 31-bx): uniform 33
// j-steps per block. j-tile 64, double-buffered K/V (32KB LDS, 4 blocks/CU),
// one barrier per tile, prefetch issued before compute. Swizzles: 16B-chunk
// XOR (row&7), both-sides involution -> 2-way max on reads (free).
__global__ __launch_bounds__(256, 4) void attn(
    const bf16* __restrict__ Qn, const bf16* __restrict__ Kn, const bf16* __restrict__ Vt,
    bf16* __restrict__ O)
{
  __shared__ __align__(16) bf16 Ks[2][64 * 64];   // [j][d]
  __shared__ __align__(16) bf16 Vs[2][64 * 64];   // [d][j]

  const int id = blockIdx.x;
  const int bh = ((id >> 7) << 3) | (id & 7);     // same-bh blocks share an XCD
  const int bxi = (id >> 3) & 15;
  const int t = threadIdx.x, wave = t >> 6, lane = t & 63;
  const int q = lane >> 4, ln = lane & 15;
  const int b = bh >> 4, h = bh & 15;

  // staging: 2 chunks of 16B per tensor per thread (u0, u0+2048 elems)
  const int u0 = t * 8, u1 = t * 8 + 2048;
  const int kr0 = u0 >> 6, kc0 = ((u0 >> 3) & 7) ^ (kr0 & 7);
  const int kr1 = u1 >> 6, kc1 = ((u1 >> 3) & 7) ^ (kr1 & 7);
  const int vd0 = u0 >> 6, vc0 = ((u0 >> 3) & 7) ^ (vd0 & 7);
  const int vd1 = u1 >> 6, vc1 = ((u1 >> 3) & 7) ^ (vd1 & 7);
  const bf16* Kb = Kn + (size_t)bh * SEQ * HD;
  const bf16* Vb = Vt + (size_t)bh * HD * SEQ;

  f32x4 zero4 = {0.f, 0.f, 0.f, 0.f};

  for (int pass = 0; pass < 2; ++pass) {
    const int itile = pass ? (31 - bxi) : bxi;
    const int qbase = itile * 64 + wave * 16;

    // Q fragments (B-operand of S^T mfma): Q[i=qbase+ln][d=ks*32+q*8 ..+8]
    const bf16* qp = Qn + ((size_t)bh * SEQ + qbase + ln) * HD + q * 8;
    bf16x8 qf0 = *reinterpret_cast<const bf16x8*>(qp);
    bf16x8 qf1 = *reinterpret_cast<const bf16x8*>(qp + 32);

    float lrow = 0.f;
    f32x4 oacc[4];                          // [md] tiles of O^T[d][i]
#pragma unroll
    for (int md = 0; md < 4; md++) oacc[md] = zero4;

    const int nj = itile + 1;               // 64-j tiles covering 0..i0+63

    __syncthreads();                        // prior pass/iter reads done before overwrite
    {                                       // prologue: stage jt=0 into buf 0
      gld_lds16(Kb + (size_t)kr0 * HD + kc0 * 8, &Ks[0][u0]);
      gld_lds16(Kb + (size_t)kr1 * HD + kc1 * 8, &Ks[0][u1]);
      gld_lds16(Vb + (size_t)vd0 * SEQ + vc0 * 8, &Vs[0][u0]);
      gld_lds16(Vb + (size_t)vd1 * SEQ + vc1 * 8, &Vs[0][u1]);
    }

    for (int jt = 0; jt < nj; ++jt) {
      const int buf = jt & 1;
      const int j0 = jt * 64;
      __syncthreads();                      // buf staged & visible; buf^1 reads drained
      if (jt + 1 < nj) {                    // prefetch next tile into other buffer
        const int jn = j0 + 64;
        gld_lds16(Kb + (size_t)(jn + kr0) * HD + kc0 * 8, &Ks[buf ^ 1][u0]);
        gld_lds16(Kb + (size_t)(jn + kr1) * HD + kc1 * 8, &Ks[buf ^ 1][u1]);
        gld_lds16(Vb + (size_t)vd0 * SEQ + jn + vc0 * 8, &Vs[buf ^ 1][u0]);
        gld_lds16(Vb + (size_t)vd1 * SEQ + jn + vc1 * 8, &Vs[buf ^ 1][u1]);
      }

#pragma unroll
      for (int jb = 0; jb < 4; ++jb) {
        const int jslab = j0 + jb * 16;
        if (jslab <= qbase + 15) {          // slab has unmasked elems for this wave
          const int rowj = jb * 16 + ln;
          bf16x8 kf0 = *reinterpret_cast<const bf16x8*>(
              &Ks[buf][rowj * 64 + ((q)     ^ (rowj & 7)) * 8]);
          bf16x8 kf1 = *reinterpret_cast<const bf16x8*>(
              &Ks[buf][rowj * 64 + ((4 + q) ^ (rowj & 7)) * 8]);
          f32x4 z = zero4;
          z = __builtin_amdgcn_mfma_f32_16x16x32_bf16(kf0, qf0, z, 0, 0, 0);
          z = __builtin_amdgcn_mfma_f32_16x16x32_bf16(kf1, qf1, z, 0, 0, 0);
          // z[r] = S^T[j = jslab+q*4+r][i = qbase+ln]
          if (jslab + 15 > qbase) {         // partial slab: mask
#pragma unroll
            for (int r = 0; r < 4; r++) {
              int jj = jslab + q * 4 + r;
              int ii = qbase + ln;
              if (jj > ii) z[r] = -1.0e30f;
            }
          }
          // fixed-max softmax (|s*log2e| <= 2.9 after per-head LN): p = 2^s
          float p0 = exp2f(z[0]), p1 = exp2f(z[1]), p2 = exp2f(z[2]), p3 = exp2f(z[3]);
          lrow += (p0 + p1) + (p2 + p3);
          bf16x4 pk = { (bf16)p0, (bf16)p1, (bf16)p2, (bf16)p3 };   // B-frag (k=j, n=i)

          // O^T += V^T * P^T for this 16-j slab
#pragma unroll
          for (int md = 0; md < 4; md++) {
            const int rowd = md * 16 + ln;
            const bf16* vp = &Vs[buf][rowd * 64 +
                (((jb * 2 + (q >> 1)) ^ (rowd & 7)) * 8) + (q & 1) * 4];
            bf16x4 vf = *reinterpret_cast<const bf16x4*>(vp);
            oacc[md] = mfma_pv(vf, pk, oacc[md]);
          }
        }
      }
    }

    // epilogue: reduce l over the 4 quads holding each column i, normalize, store
    float s = lrow;
    s += __shfl_xor(s, 16, 64);
    s += __shfl_xor(s, 32, 64);
    const float inv = 1.f / s;
    const int row = qbase + ln;
#pragma unroll
    for (int md = 0; md < 4; md++) {
      bf16x4 o4 = { (bf16)(oacc[md][0] * inv), (bf16)(oacc[md][1] * inv),
                    (bf16)(oacc[md][2] * inv), (bf16)(oacc[md][3] * inv) };
      int col = h * HD + md * 16 + q * 4;    // 4 consecutive d
      *reinterpret_cast<bf16x4*>(&O[(size_t)(b * SEQ + row) * EMB + col]) = o4;
    }
  }
}

// ---------------- launch ----------------
extern "C" void kernel_launch(void* const* d_in, const int* in_sizes, int n_in,
                              void* d_out, int out_size, void* d_ws, size_t ws_size,
                              hipStream_t stream)
{
  const float* x   = (const float*)d_in[0];
  const float* Wk  = (const float*)d_in[1];
  const float* Wq  = (const float*)d_in[2];
  const float* Wv  = (const float*)d_in[3];
  const float* Wo  = (const float*)d_in[4];
  const float* bo  = (const float*)d_in[5];
  const float* klg = (const float*)d_in[6];
  const float* klb = (const float*)d_in[7];
  const float* qlg = (const float*)d_in[8];
  const float* qlb = (const float*)d_in[9];
  float* out = (float*)d_out;

  char* ws = (char*)d_ws;
  const size_t OFF_XB  = 0;
  const size_t OFF_WB  = OFF_XB  + (size_t)BT * EMB * 2;
  const size_t OFF_KQV = OFF_WB  + (size_t)4 * EMB * EMB * 2;
  const size_t OFF_KN  = OFF_KQV + (size_t)BT * 3 * EMB * 2;
  const size_t OFF_QN  = OFF_KN  + (size_t)BT * EMB * 2;
  const size_t OFF_VT  = OFF_QN  + (size_t)BT * EMB * 2;
  const size_t OFF_END = OFF_VT  + (size_t)BT * EMB * 2;
  if (ws_size < OFF_END) return;

  bf16* xb   = (bf16*)(ws + OFF_XB);
  bf16* wb   = (bf16*)(ws + OFF_WB);
  bf16* kn   = (bf16*)(ws + OFF_KN);
  bf16* qn   = (bf16*)(ws + OFF_QN);
  bf16* vt   = (bf16*)(ws + OFF_VT);
  bf16* ob   = (bf16*)(ws + OFF_KQV);    // attn output (KQV region unused otherwise)

  cvt_all<<<12288, 256, 0, stream>>>(x, Wk, Wq, Wv, Wo, xb, wb);

  gemm_kqv<<<dim3(3 * EMB / 128, BT / 128), 256, 0, stream>>>(
      xb, wb, kn, qn, vt, klg, klb, qlg, qlb);

  attn<<<dim3(16 * BATCH * HEADS), 256, 0, stream>>>(qn, kn, vt, ob);

  gemm_bt<1><<<dim3(EMB / 128, BT / 128), 256, 0, stream>>>(
      ob, wb + (size_t)3 * EMB * EMB, (bf16*)nullptr, out, bo, BT, EMB, EMB);
}

// Round 8
// 259.143 us; speedup vs baseline: 1.1731x; 1.0311x over previous
//
#include <hip/hip_runtime.h>
#include <hip/hip_bf16.h>
#include <cstdint>

#define EMB 1024
#define HEADS 16
#define HD 64
#define BATCH 4
#define SEQ 2048
#define BT (BATCH*SEQ)                 // 8192 tokens
#define LNEPS 1e-5f
#define QK_SCALE 0.17677669529663687f  // 1024^-0.25
#define LOG2E 1.4426950408889634f

typedef __bf16 bf16;
typedef __bf16 bf16x8 __attribute__((ext_vector_type(8)));
typedef __bf16 bf16x4 __attribute__((ext_vector_type(4)));
typedef float  f32x4  __attribute__((ext_vector_type(4)));
typedef short  s16x4  __attribute__((ext_vector_type(4)));

typedef const __attribute__((address_space(1))) void* gas_ptr;
typedef __attribute__((address_space(3))) void*       las_ptr;

__device__ __forceinline__ void gld_lds16(const void* g, void* l) {
  __builtin_amdgcn_global_load_lds((gas_ptr)g, (las_ptr)l, 16, 0, 0);
}

// PV matmul: 16x16x16 bf16 MFMA (C-layout of S^T == B-layout of this shape).
__device__ __forceinline__ f32x4 mfma_pv(bf16x4 a, bf16x4 b, f32x4 c) {
  return __builtin_amdgcn_mfma_f32_16x16x16bf16_1k(
      __builtin_bit_cast(s16x4, a), __builtin_bit_cast(s16x4, b), c, 0, 0, 0);
}

// ---------------- fused fp32->bf16 conversions (x + 4 weight mats) ----------------
// blocks [0,8192): x (2M float4); blocks [8192,12288): W4 (1M float4).
__global__ void cvt_all(const float* __restrict__ x,
                        const float* __restrict__ w0, const float* __restrict__ w1,
                        const float* __restrict__ w2, const float* __restrict__ w3,
                        bf16* __restrict__ xb, bf16* __restrict__ wb) {
  const int bid = blockIdx.x;
  if (bid < 8192) {
    int i = bid * 256 + threadIdx.x;           // over BT*EMB/4 float4s
    float4 f = reinterpret_cast<const float4*>(x)[i];
    bf16x4 o = { (bf16)f.x, (bf16)f.y, (bf16)f.z, (bf16)f.w };
    reinterpret_cast<bf16x4*>(xb)[i] = o;
  } else {
    int i = (bid - 8192) * 256 + threadIdx.x;  // over 4*EMB*EMB/4 float4s
    int sel = i >> 18;
    int j = i & 262143;
    const float* s = (sel == 0) ? w0 : (sel == 1) ? w1 : (sel == 2) ? w2 : w3;
    float4 f = reinterpret_cast<const float4*>(s)[j];
    bf16x4 o = { (bf16)f.x, (bf16)f.y, (bf16)f.z, (bf16)f.w };
    reinterpret_cast<bf16x4*>(wb)[i] = o;
  }
}

// ======== shared dbuf-BK64 GEMM core (this round's change) ========
// K-loop: BK=64, double-buffered LDS (2 x 16KB per tensor = 64KB/block,
// 2 blocks/CU), ONE barrier per K-tile (was 2 per 32-K step = 64/kernel;
// now 16), prefetch of tile kt+1 issued before compute of kt (attn r1
// pattern). Rows are 128B -> naive read bank = chunk*4 (row-independent)
// = 16-way conflict; fix: 16B-chunk XOR (row&7), BOTH at the pre-swizzled
// global source and the fragment read (rule 21). Fragment chunk (ks*4+q)
// ^ (row&7): each 16-lane group covers all 8 slots -> 2-way max (free).
#define GEMM_DBUF_LOOP(A_, B_, K_)                                            \
  f32x4 zero4 = {0.f, 0.f, 0.f, 0.f};                                         \
  f32x4 acc[4][4];                                                            \
  _Pragma("unroll")                                                           \
  for (int i = 0; i < 4; i++)                                                 \
    _Pragma("unroll")                                                         \
    for (int j = 0; j < 4; j++) acc[i][j] = zero4;                            \
  {                                                                           \
    _Pragma("unroll")                                                         \
    for (int i = 0; i < 4; i++) {                                             \
      const int u = t * 8 + i * 2048;                                         \
      const int row = u >> 6;                                                 \
      const int c = ((u >> 3) & 7) ^ (row & 7);                               \
      gld_lds16(A_ + (size_t)(m0 + row) * K_ + c * 8, &As[0][u]);             \
      gld_lds16(B_ + (size_t)(n0 + row) * K_ + c * 8, &Bs[0][u]);             \
    }                                                                         \
  }                                                                           \
  for (int kt = 0; kt < K_ / 64; ++kt) {                                      \
    const int buf = kt & 1;                                                   \
    __syncthreads();                                                          \
    if (kt + 1 < K_ / 64) {                                                   \
      const int k0 = (kt + 1) * 64;                                           \
      _Pragma("unroll")                                                       \
      for (int i = 0; i < 4; i++) {                                           \
        const int u = t * 8 + i * 2048;                                       \
        const int row = u >> 6;                                               \
        const int c = ((u >> 3) & 7) ^ (row & 7);                             \
        gld_lds16(A_ + (size_t)(m0 + row) * K_ + k0 + c * 8, &As[buf^1][u]);  \
        gld_lds16(B_ + (size_t)(n0 + row) * K_ + k0 + c * 8, &Bs[buf^1][u]);  \
      }                                                                       \
    }                                                                         \
    _Pragma("unroll")                                                         \
    for (int ks = 0; ks < 2; ++ks) {                                          \
      bf16x8 af[4], bfr[4];                                                   \
      _Pragma("unroll")                                                       \
      for (int mi = 0; mi < 4; mi++) {                                        \
        const int row = wm + mi * 16 + ln;                                    \
        af[mi] = *reinterpret_cast<const bf16x8*>(                            \
            &As[buf][row * 64 + ((ks * 4 + q) ^ (row & 7)) * 8]);             \
      }                                                                       \
      _Pragma("unroll")                                                       \
      for (int ni = 0; ni < 4; ni++) {                                        \
        const int row = wn + ni * 16 + ln;                                    \
        bfr[ni] = *reinterpret_cast<const bf16x8*>(                           \
            &Bs[buf][row * 64 + ((ks * 4 + q) ^ (row & 7)) * 8]);             \
      }                                                                       \
      _Pragma("unroll")                                                       \
      for (int mi = 0; mi < 4; mi++)                                          \
        _Pragma("unroll")                                                     \
        for (int ni = 0; ni < 4; ni++)                                        \
          acc[mi][ni] = __builtin_amdgcn_mfma_f32_16x16x32_bf16(              \
              af[mi], bfr[ni], acc[mi][ni], 0, 0, 0);                         \
    }                                                                         \
  }

// ---------------- fused QKV GEMM + per-head LN(K,Q) + V transpose ----------------
// C[8192][3072] = xb * wb^T; C never hits memory:
//   cols [0,1024):   K-proj -> per-head LN (scale QK_SCALE*LOG2E) -> kn [bh][t][64]
//   cols [1024,2048) Q-proj -> per-head LN (scale QK_SCALE)       -> qn [bh][t][64]
//   cols [2048,3072) V-proj ->                                       vt [bh][64][2048]
// XCD-affine remap (grid 24x64): per-XCD resident panels ~4MB = its L2.
__global__ __launch_bounds__(256, 2) void gemm_kqv(
    const bf16* __restrict__ A, const bf16* __restrict__ Bm,
    bf16* __restrict__ kn, bf16* __restrict__ qn, bf16* __restrict__ vt,
    const float* __restrict__ kg, const float* __restrict__ kb,
    const float* __restrict__ qg, const float* __restrict__ qb)
{
  __shared__ __align__(16) bf16 As[2][128 * 64];
  __shared__ __align__(16) bf16 Bs[2][128 * 64];

  const int t    = threadIdx.x;
  const int lane = t & 63;
  const int wave = t >> 6;
  const int q    = lane >> 4;
  const int ln   = lane & 15;

  const int lid = (int)blockIdx.y * (int)gridDim.x + (int)blockIdx.x;
  const int xcd = lid & 7;
  const int nn  = lid >> 3;
  const int bxr = nn >> 3;                 // [0, 24)
  const int byr = (xcd << 3) | (nn & 7);   // [0, 64)
  const int m0  = byr * 128;
  const int n0  = bxr * 128;

  const int wm = (wave >> 1) * 64;
  const int wn = (wave & 1) * 64;

  GEMM_DBUF_LOOP(A, Bm, EMB)

  // ---- epilogue (unchanged from round 6, verified) ----
  const int sec = n0 >> 10;                 // 0=K, 1=Q, 2=V
  const int cb  = (n0 & 1023) + wn;         // col within projection
  const int h   = cb >> 6;                  // head
  const int R0  = m0 + wm;

  if (sec == 2) {
    // V: write transposed [bh][d][t]; lane holds 4 consecutive t at fixed d
#pragma unroll
    for (int mi = 0; mi < 4; mi++) {
      const int R = R0 + mi * 16 + q * 4;
      const int b = R >> 11, tt = R & 2047;
#pragma unroll
      for (int ni = 0; ni < 4; ni++) {
        const int d = ni * 16 + ln;
        bf16x4 o4 = { (bf16)acc[mi][ni][0], (bf16)acc[mi][ni][1],
                      (bf16)acc[mi][ni][2], (bf16)acc[mi][ni][3] };
        *reinterpret_cast<bf16x4*>(
            &vt[((size_t)(b * HEADS + h) * HD + d) * SEQ + tt]) = o4;
      }
    }
  } else {
    const float scale = sec ? QK_SCALE : (QK_SCALE * LOG2E);
    const float* gp = sec ? qg : kg;
    const float* bp = sec ? qb : kb;
    bf16* outp = sec ? qn : kn;
    float gv[4], bv[4];
#pragma unroll
    for (int ni = 0; ni < 4; ni++) {
      gv[ni] = gp[ni * 16 + ln];
      bv[ni] = bp[ni * 16 + ln] * scale;
    }
#pragma unroll
    for (int mi = 0; mi < 4; mi++) {
#pragma unroll
      for (int r = 0; r < 4; r++) {
        const float x0 = acc[mi][0][r], x1 = acc[mi][1][r];
        const float x2 = acc[mi][2][r], x3 = acc[mi][3][r];
        float s  = (x0 + x1) + (x2 + x3);
        float s2 = (x0 * x0 + x1 * x1) + (x2 * x2 + x3 * x3);
#pragma unroll
        for (int mm = 1; mm < 16; mm <<= 1) {
          s  += __shfl_xor(s,  mm, 64);
          s2 += __shfl_xor(s2, mm, 64);
        }
        const float mean = s * (1.f / 64.f);
        const float rs = rsqrtf(s2 * (1.f / 64.f) - mean * mean + LNEPS) * scale;
        const int R = R0 + mi * 16 + q * 4 + r;
        const int b = R >> 11, tt = R & 2047;
        const size_t o = ((size_t)(b * HEADS + h) * SEQ + tt) * HD + ln;
#pragma unroll
        for (int ni = 0; ni < 4; ni++)
          outp[o + ni * 16] = (bf16)((acc[mi][ni][r] - mean) * rs * gv[ni] + bv[ni]);
      }
    }
  }
}

// ---------------- output-proj GEMM: out[M][N] = A[M][K] * B[N][K]^T + bias ----------------
// Same XCD-affine remap (requires gridDim.y == 64) + dbuf BK=64 loop.
__global__ __launch_bounds__(256, 2) void gemm_out(
    const bf16* __restrict__ A, const bf16* __restrict__ Bm,
    float* __restrict__ Cf, const float* __restrict__ bias, int N)
{
  __shared__ __align__(16) bf16 As[2][128 * 64];
  __shared__ __align__(16) bf16 Bs[2][128 * 64];

  const int t    = threadIdx.x;
  const int lane = t & 63;
  const int wave = t >> 6;
  const int q    = lane >> 4;
  const int ln   = lane & 15;

  const int lid = (int)blockIdx.y * (int)gridDim.x + (int)blockIdx.x;
  const int xcd = lid & 7;
  const int nn  = lid >> 3;
  const int bxr = nn >> 3;                 // [0, gridDim.x)
  const int byr = (xcd << 3) | (nn & 7);   // [0, 64)
  const int m0  = byr * 128;
  const int n0  = bxr * 128;

  const int wm = (wave >> 1) * 64;
  const int wn = (wave & 1) * 64;

  GEMM_DBUF_LOOP(A, Bm, EMB)

#pragma unroll
  for (int mi = 0; mi < 4; mi++) {
#pragma unroll
    for (int ni = 0; ni < 4; ni++) {
#pragma unroll
      for (int r = 0; r < 4; r++) {
        int row = m0 + wm + mi * 16 + q * 4 + r;
        int col = n0 + wn + ni * 16 + ln;
        Cf[(size_t)row * N + col] = acc[mi][ni][r] + bias[col];
      }
    }
  }
}

// ---------------- flash attention (causal), S^T form, paired tiles + dbuf ----------------
// 1-D grid of 1024 blocks, XCD-affine decode: xcd=id&7, bx=(id>>3)&15,
// bh=(id>>7)*8+xcd -> all 16 blocks of a bh on ONE XCD (its L2 holds 8 bhs'
// K/V; FETCH 255->25MB, round 3). Pass pairing (bx then 31-bx): uniform 33
// j-steps per block. j-tile 64, double-buffered K/V (32KB LDS, 4 blocks/CU),
// one barrier per tile, prefetch issued before compute. Swizzles: 16B-chunk
// XOR (row&7), both-sides involution -> 2-way max on reads (free).
__global__ __launch_bounds__(256, 4) void attn(
    const bf16* __restrict__ Qn, const bf16* __restrict__ Kn, const bf16* __restrict__ Vt,
    bf16* __restrict__ O)
{
  __shared__ __align__(16) bf16 Ks[2][64 * 64];   // [j][d]
  __shared__ __align__(16) bf16 Vs[2][64 * 64];   // [d][j]

  const int id = blockIdx.x;
  const int bh = ((id >> 7) << 3) | (id & 7);     // same-bh blocks share an XCD
  const int bxi = (id >> 3) & 15;
  const int t = threadIdx.x, wave = t >> 6, lane = t & 63;
  const int q = lane >> 4, ln = lane & 15;
  const int b = bh >> 4, h = bh & 15;

  // staging: 2 chunks of 16B per tensor per thread (u0, u0+2048 elems)
  const int u0 = t * 8, u1 = t * 8 + 2048;
  const int kr0 = u0 >> 6, kc0 = ((u0 >> 3) & 7) ^ (kr0 & 7);
  const int kr1 = u1 >> 6, kc1 = ((u1 >> 3) & 7) ^ (kr1 & 7);
  const int vd0 = u0 >> 6, vc0 = ((u0 >> 3) & 7) ^ (vd0 & 7);
  const int vd1 = u1 >> 6, vc1 = ((u1 >> 3) & 7) ^ (vd1 & 7);
  const bf16* Kb = Kn + (size_t)bh * SEQ * HD;
  const bf16* Vb = Vt + (size_t)bh * HD * SEQ;

  f32x4 zero4 = {0.f, 0.f, 0.f, 0.f};

  for (int pass = 0; pass < 2; ++pass) {
    const int itile = pass ? (31 - bxi) : bxi;
    const int qbase = itile * 64 + wave * 16;

    // Q fragments (B-operand of S^T mfma): Q[i=qbase+ln][d=ks*32+q*8 ..+8]
    const bf16* qp = Qn + ((size_t)bh * SEQ + qbase + ln) * HD + q * 8;
    bf16x8 qf0 = *reinterpret_cast<const bf16x8*>(qp);
    bf16x8 qf1 = *reinterpret_cast<const bf16x8*>(qp + 32);

    float lrow = 0.f;
    f32x4 oacc[4];                          // [md] tiles of O^T[d][i]
#pragma unroll
    for (int md = 0; md < 4; md++) oacc[md] = zero4;

    const int nj = itile + 1;               // 64-j tiles covering 0..i0+63

    __syncthreads();                        // prior pass/iter reads done before overwrite
    {                                       // prologue: stage jt=0 into buf 0
      gld_lds16(Kb + (size_t)kr0 * HD + kc0 * 8, &Ks[0][u0]);
      gld_lds16(Kb + (size_t)kr1 * HD + kc1 * 8, &Ks[0][u1]);
      gld_lds16(Vb + (size_t)vd0 * SEQ + vc0 * 8, &Vs[0][u0]);
      gld_lds16(Vb + (size_t)vd1 * SEQ + vc1 * 8, &Vs[0][u1]);
    }

    for (int jt = 0; jt < nj; ++jt) {
      const int buf = jt & 1;
      const int j0 = jt * 64;
      __syncthreads();                      // buf staged & visible; buf^1 reads drained
      if (jt + 1 < nj) {                    // prefetch next tile into other buffer
        const int jn = j0 + 64;
        gld_lds16(Kb + (size_t)(jn + kr0) * HD + kc0 * 8, &Ks[buf ^ 1][u0]);
        gld_lds16(Kb + (size_t)(jn + kr1) * HD + kc1 * 8, &Ks[buf ^ 1][u1]);
        gld_lds16(Vb + (size_t)vd0 * SEQ + jn + vc0 * 8, &Vs[buf ^ 1][u0]);
        gld_lds16(Vb + (size_t)vd1 * SEQ + jn + vc1 * 8, &Vs[buf ^ 1][u1]);
      }

#pragma unroll
      for (int jb = 0; jb < 4; ++jb) {
        const int jslab = j0 + jb * 16;
        if (jslab <= qbase + 15) {          // slab has unmasked elems for this wave
          const int rowj = jb * 16 + ln;
          bf16x8 kf0 = *reinterpret_cast<const bf16x8*>(
              &Ks[buf][rowj * 64 + ((q)     ^ (rowj & 7)) * 8]);
          bf16x8 kf1 = *reinterpret_cast<const bf16x8*>(
              &Ks[buf][rowj * 64 + ((4 + q) ^ (rowj & 7)) * 8]);
          f32x4 z = zero4;
          z = __builtin_amdgcn_mfma_f32_16x16x32_bf16(kf0, qf0, z, 0, 0, 0);
          z = __builtin_amdgcn_mfma_f32_16x16x32_bf16(kf1, qf1, z, 0, 0, 0);
          // z[r] = S^T[j = jslab+q*4+r][i = qbase+ln]
          if (jslab + 15 > qbase) {         // partial slab: mask
#pragma unroll
            for (int r = 0; r < 4; r++) {
              int jj = jslab + q * 4 + r;
              int ii = qbase + ln;
              if (jj > ii) z[r] = -1.0e30f;
            }
          }
          // fixed-max softmax (|s*log2e| <= 2.9 after per-head LN): p = 2^s
          float p0 = exp2f(z[0]), p1 = exp2f(z[1]), p2 = exp2f(z[2]), p3 = exp2f(z[3]);
          lrow += (p0 + p1) + (p2 + p3);
          bf16x4 pk = { (bf16)p0, (bf16)p1, (bf16)p2, (bf16)p3 };   // B-frag (k=j, n=i)

          // O^T += V^T * P^T for this 16-j slab
#pragma unroll
          for (int md = 0; md < 4; md++) {
            const int rowd = md * 16 + ln;
            const bf16* vp = &Vs[buf][rowd * 64 +
                (((jb * 2 + (q >> 1)) ^ (rowd & 7)) * 8) + (q & 1) * 4];
            bf16x4 vf = *reinterpret_cast<const bf16x4*>(vp);
            oacc[md] = mfma_pv(vf, pk, oacc[md]);
          }
        }
      }
    }

    // epilogue: reduce l over the 4 quads holding each column i, normalize, store
    float s = lrow;
    s += __shfl_xor(s, 16, 64);
    s += __shfl_xor(s, 32, 64);
    const float inv = 1.f / s;
    const int row = qbase + ln;
#pragma unroll
    for (int md = 0; md < 4; md++) {
      bf16x4 o4 = { (bf16)(oacc[md][0] * inv), (bf16)(oacc[md][1] * inv),
                    (bf16)(oacc[md][2] * inv), (bf16)(oacc[md][3] * inv) };
      int col = h * HD + md * 16 + q * 4;    // 4 consecutive d
      *reinterpret_cast<bf16x4*>(&O[(size_t)(b * SEQ + row) * EMB + col]) = o4;
    }
  }
}

// ---------------- launch ----------------
extern "C" void kernel_launch(void* const* d_in, const int* in_sizes, int n_in,
                              void* d_out, int out_size, void* d_ws, size_t ws_size,
                              hipStream_t stream)
{
  const float* x   = (const float*)d_in[0];
  const float* Wk  = (const float*)d_in[1];
  const float* Wq  = (const float*)d_in[2];
  const float* Wv  = (const float*)d_in[3];
  const float* Wo  = (const float*)d_in[4];
  const float* bo  = (const float*)d_in[5];
  const float* klg = (const float*)d_in[6];
  const float* klb = (const float*)d_in[7];
  const float* qlg = (const float*)d_in[8];
  const float* qlb = (const float*)d_in[9];
  float* out = (float*)d_out;

  char* ws = (char*)d_ws;
  const size_t OFF_XB  = 0;
  const size_t OFF_WB  = OFF_XB  + (size_t)BT * EMB * 2;
  const size_t OFF_KQV = OFF_WB  + (size_t)4 * EMB * EMB * 2;
  const size_t OFF_KN  = OFF_KQV + (size_t)BT * 3 * EMB * 2;
  const size_t OFF_QN  = OFF_KN  + (size_t)BT * EMB * 2;
  const size_t OFF_VT  = OFF_QN  + (size_t)BT * EMB * 2;
  const size_t OFF_END = OFF_VT  + (size_t)BT * EMB * 2;
  if (ws_size < OFF_END) return;

  bf16* xb   = (bf16*)(ws + OFF_XB);
  bf16* wb   = (bf16*)(ws + OFF_WB);
  bf16* kn   = (bf16*)(ws + OFF_KN);
  bf16* qn   = (bf16*)(ws + OFF_QN);
  bf16* vt   = (bf16*)(ws + OFF_VT);
  bf16* ob   = (bf16*)(ws + OFF_KQV);    // attn output (KQV region unused otherwise)

  cvt_all<<<12288, 256, 0, stream>>>(x, Wk, Wq, Wv, Wo, xb, wb);

  gemm_kqv<<<dim3(3 * EMB / 128, BT / 128), 256, 0, stream>>>(
      xb, wb, kn, qn, vt, klg, klb, qlg, qlb);

  attn<<<dim3(16 * BATCH * HEADS), 256, 0, stream>>>(qn, kn, vt, ob);

  gemm_out<<<dim3(EMB / 128, BT / 128), 256, 0, stream>>>(
      ob, wb + (size_t)3 * EMB * EMB, out, bo, EMB);
}